// Round 1
// baseline (808.020 us; speedup 1.0000x reference)
//
#include <hip/hip_runtime.h>

#define THREADS 256

// ---------------- degree / norm ----------------

__global__ void k_init_deg(float* __restrict__ deg, int n) {
  int i = blockIdx.x * blockDim.x + threadIdx.x;
  if (i < n) deg[i] = 1.0f;  // self-loop
}

__global__ void k_count(const int* __restrict__ dst, float* __restrict__ deg, int e) {
  int i = blockIdx.x * blockDim.x + threadIdx.x;
  if (i < e) unsafeAtomicAdd(&deg[dst[i]], 1.0f);
}

__global__ void k_dinv(float* __restrict__ d, int n) {
  int i = blockIdx.x * blockDim.x + threadIdx.x;
  if (i < n) d[i] = rsqrtf(d[i]);
}

// ---------------- GEMM1: h1[n][64] = x[n][128] @ W1[64][128]^T ----------------
// block: 256 threads -> 64 rows x 64 cols, 4x4 microtile per thread.
// W1 in LDS, XOR-swizzled so float4 reads over k are bank-conflict-free.
// x read directly from global (each row owned by one wave; broadcast within wave).

__launch_bounds__(256)
__global__ void k_gemm1(const float* __restrict__ x, const float* __restrict__ W1,
                        float* __restrict__ h1, int n) {
  __shared__ float sW[64 * 128];
  int t = threadIdx.x;
  for (int idx = t; idx < 64 * 128; idx += 256) {
    int c = idx >> 7, k = idx & 127;
    sW[(c << 7) | (k ^ (((c >> 2) & 7) << 2))] = W1[idx];
  }
  __syncthreads();
  int r0 = blockIdx.x * 64;
  int tr = r0 + ((t >> 4) << 2);
  int tc = (t & 15) << 2;
  float acc[4][4] = {{0.f}};
  for (int kq = 0; kq < 32; ++kq) {
    float4 xv[4], wv[4];
#pragma unroll
    for (int i = 0; i < 4; ++i) {
      if (tr + i < n)
        xv[i] = *(const float4*)&x[(size_t)(tr + i) * 128 + (kq << 2)];
      else
        xv[i] = make_float4(0.f, 0.f, 0.f, 0.f);
    }
#pragma unroll
    for (int j = 0; j < 4; ++j) {
      int c = tc + j;
      wv[j] = *(const float4*)&sW[(c << 7) | ((kq << 2) ^ (((c >> 2) & 7) << 2))];
    }
#pragma unroll
    for (int i = 0; i < 4; ++i)
#pragma unroll
      for (int j = 0; j < 4; ++j) {
        acc[i][j] = fmaf(xv[i].x, wv[j].x, acc[i][j]);
        acc[i][j] = fmaf(xv[i].y, wv[j].y, acc[i][j]);
        acc[i][j] = fmaf(xv[i].z, wv[j].z, acc[i][j]);
        acc[i][j] = fmaf(xv[i].w, wv[j].w, acc[i][j]);
      }
  }
#pragma unroll
  for (int i = 0; i < 4; ++i) {
    int gr = tr + i;
    if (gr < n)
      *(float4*)&h1[(size_t)gr * 64 + tc] =
          make_float4(acc[i][0], acc[i][1], acc[i][2], acc[i][3]);
  }
}

// ---------------- self-loop init: agg1 = dinv^2 * h1 ----------------

__global__ void k_self1(const float4* __restrict__ h1, const float* __restrict__ dinv,
                        float4* __restrict__ agg1, int n16) {
  int i = blockIdx.x * blockDim.x + threadIdx.x;  // over n*16 float4s
  if (i < n16) {
    float d = dinv[i >> 4];
    float s = d * d;
    float4 v = h1[i];
    agg1[i] = make_float4(v.x * s, v.y * s, v.z * s, v.w * s);
  }
}

// ---------------- scatter1: agg1[dst] += norm * h1[src], 64 feats ----------------

__global__ void k_scatter1(const float* __restrict__ h1, const float* __restrict__ dinv,
                           const int* __restrict__ src, const int* __restrict__ dst,
                           float* __restrict__ agg1, int e) {
  int gid = blockIdx.x * blockDim.x + threadIdx.x;
  int ei = gid >> 6, lane = gid & 63;
  if (ei < e) {
    int s = src[ei], d = dst[ei];
    float nm = dinv[s] * dinv[d];
    unsafeAtomicAdd(&agg1[(size_t)d * 64 + lane], nm * h1[(size_t)s * 64 + lane]);
  }
}

// ---------------- GEMM2: h2[n][32] = relu(agg1 + b1) @ W2[32][64]^T ----------------
// block: 256 threads -> 128 rows x 32 cols, 4x4 microtile.

__launch_bounds__(256)
__global__ void k_gemm2(const float* __restrict__ agg1, const float* __restrict__ b1,
                        const float* __restrict__ W2, float* __restrict__ h2, int n) {
  __shared__ float sW[32 * 64];
  __shared__ float sb[64];
  int t = threadIdx.x;
  if (t < 64) sb[t] = b1[t];
  for (int idx = t; idx < 32 * 64; idx += 256) {
    int c = idx >> 6, k = idx & 63;
    sW[(c << 6) | (k ^ (((c >> 2) & 7) << 2))] = W2[idx];
  }
  __syncthreads();
  int r0 = blockIdx.x * 128;
  int tr = r0 + ((t >> 3) << 2);
  int tc = (t & 7) << 2;
  float acc[4][4] = {{0.f}};
  for (int kq = 0; kq < 16; ++kq) {
    float4 bv = *(const float4*)&sb[kq << 2];
    float4 xv[4], wv[4];
#pragma unroll
    for (int i = 0; i < 4; ++i) {
      if (tr + i < n) {
        float4 v = *(const float4*)&agg1[(size_t)(tr + i) * 64 + (kq << 2)];
        xv[i] = make_float4(fmaxf(v.x + bv.x, 0.f), fmaxf(v.y + bv.y, 0.f),
                            fmaxf(v.z + bv.z, 0.f), fmaxf(v.w + bv.w, 0.f));
      } else {
        xv[i] = make_float4(0.f, 0.f, 0.f, 0.f);
      }
    }
#pragma unroll
    for (int j = 0; j < 4; ++j) {
      int c = tc + j;
      wv[j] = *(const float4*)&sW[(c << 6) | ((kq << 2) ^ (((c >> 2) & 7) << 2))];
    }
#pragma unroll
    for (int i = 0; i < 4; ++i)
#pragma unroll
      for (int j = 0; j < 4; ++j) {
        acc[i][j] = fmaf(xv[i].x, wv[j].x, acc[i][j]);
        acc[i][j] = fmaf(xv[i].y, wv[j].y, acc[i][j]);
        acc[i][j] = fmaf(xv[i].z, wv[j].z, acc[i][j]);
        acc[i][j] = fmaf(xv[i].w, wv[j].w, acc[i][j]);
      }
  }
#pragma unroll
  for (int i = 0; i < 4; ++i) {
    int gr = tr + i;
    if (gr < n)
      *(float4*)&h2[(size_t)gr * 32 + tc] =
          make_float4(acc[i][0], acc[i][1], acc[i][2], acc[i][3]);
  }
}

// ---------------- self-loop init 2: out = dinv^2 * h2 + b2 ----------------

__global__ void k_self2(const float4* __restrict__ h2, const float* __restrict__ dinv,
                        const float* __restrict__ b2, float4* __restrict__ out, int n8) {
  int i = blockIdx.x * blockDim.x + threadIdx.x;  // over n*8 float4s
  if (i < n8) {
    float d = dinv[i >> 3];
    float s = d * d;
    float4 v = h2[i];
    const float4 b = *(const float4*)&b2[(i & 7) << 2];
    out[i] = make_float4(fmaf(v.x, s, b.x), fmaf(v.y, s, b.y),
                         fmaf(v.z, s, b.z), fmaf(v.w, s, b.w));
  }
}

// ---------------- scatter2: out[dst] += norm * h2[src], 32 feats ----------------

__global__ void k_scatter2(const float* __restrict__ h2, const float* __restrict__ dinv,
                           const int* __restrict__ src, const int* __restrict__ dst,
                           float* __restrict__ out, int e) {
  int gid = blockIdx.x * blockDim.x + threadIdx.x;
  int ei = gid >> 5, lane = gid & 31;
  if (ei < e) {
    int s = src[ei], d = dst[ei];
    float nm = dinv[s] * dinv[d];
    unsafeAtomicAdd(&out[(size_t)d * 32 + lane], nm * h2[(size_t)s * 32 + lane]);
  }
}

// ---------------- launcher ----------------

extern "C" void kernel_launch(void* const* d_in, const int* in_sizes, int n_in,
                              void* d_out, int out_size, void* d_ws, size_t ws_size,
                              hipStream_t stream) {
  const float* x = (const float*)d_in[0];
  const int* ei = (const int*)d_in[1];
  const float* W1 = (const float*)d_in[2];
  const float* b1 = (const float*)d_in[3];
  const float* W2 = (const float*)d_in[4];
  const float* b2 = (const float*)d_in[5];
  float* out = (float*)d_out;

  const int n = in_sizes[0] / 128;  // 100000
  const int e = in_sizes[1] / 2;    // 1600000
  const int* src = ei;
  const int* dst = ei + e;

  float* ws = (float*)d_ws;
  size_t nn = (size_t)n;
  float* dinv = ws;
  float* h1 = ws + ((nn + 1023) & ~(size_t)1023);
  float* agg1 = h1 + nn * 64;
  float* h2 = agg1 + nn * 64;

  // 1) degrees + dinv
  k_init_deg<<<(n + THREADS - 1) / THREADS, THREADS, 0, stream>>>(dinv, n);
  k_count<<<(e + THREADS - 1) / THREADS, THREADS, 0, stream>>>(dst, dinv, e);
  k_dinv<<<(n + THREADS - 1) / THREADS, THREADS, 0, stream>>>(dinv, n);

  // 2) h1 = x @ W1^T
  k_gemm1<<<(n + 63) / 64, 256, 0, stream>>>(x, W1, h1, n);

  // 3) agg1 = selfloop + scatter
  int n16 = n * 16;
  k_self1<<<(n16 + THREADS - 1) / THREADS, THREADS, 0, stream>>>(
      (const float4*)h1, dinv, (float4*)agg1, n16);
  {
    long long total = (long long)e * 64;
    int blocks = (int)((total + THREADS - 1) / THREADS);
    k_scatter1<<<blocks, THREADS, 0, stream>>>(h1, dinv, src, dst, agg1, e);
  }

  // 4) h2 = relu(agg1 + b1) @ W2^T
  k_gemm2<<<(n + 127) / 128, 256, 0, stream>>>(agg1, b1, W2, h2, n);

  // 5) out = selfloop + b2 + scatter
  int n8 = n * 8;
  k_self2<<<(n8 + THREADS - 1) / THREADS, THREADS, 0, stream>>>(
      (const float4*)h2, dinv, b2, (float4*)out, n8);
  {
    long long total = (long long)e * 32;
    int blocks = (int)((total + THREADS - 1) / THREADS);
    k_scatter2<<<blocks, THREADS, 0, stream>>>(h2, dinv, src, dst, out, e);
  }
}

// Round 2
// 613.979 us; speedup vs baseline: 1.3160x; 1.3160x over previous
//
#include <hip/hip_runtime.h>

#define THREADS 256

// ======================= CSR build =======================

__global__ void k_zero(int* __restrict__ cnt, int n) {
  int i = blockIdx.x * blockDim.x + threadIdx.x;
  if (i < n) cnt[i] = 0;
}

__global__ void k_count(const int* __restrict__ dst, int* __restrict__ cnt, int e) {
  int i = blockIdx.x * blockDim.x + threadIdx.x;
  if (i < e) atomicAdd(&cnt[dst[i]], 1);
}

// chunk = 1024 counts per 256-thread block; exclusive scan within chunk,
// chunk total -> bsum[b]. rp has n+1 entries (rp[n] written by the chunk
// containing index n).
__global__ void k_scan_chunk(const int* __restrict__ cnt, int* __restrict__ rp,
                             int* __restrict__ bsum, int n) {
  __shared__ int s[256];
  int b = blockIdx.x, t = threadIdx.x;
  int base = b * 1024 + t * 4;
  int v[4];
  int sum = 0;
#pragma unroll
  for (int k = 0; k < 4; ++k) {
    int i = base + k;
    v[k] = (i < n) ? cnt[i] : 0;
    sum += v[k];
  }
  s[t] = sum;
  __syncthreads();
  int mine = sum;
  for (int off = 1; off < 256; off <<= 1) {
    int y = (t >= off) ? s[t - off] : 0;
    __syncthreads();
    s[t] += y;
    __syncthreads();
  }
  int run = s[t] - mine;  // exclusive prefix of this thread's 4-group
  if (t == 255) bsum[b] = s[255];
#pragma unroll
  for (int k = 0; k < 4; ++k) {
    int i = base + k;
    if (i <= n) rp[i] = run;
    run += v[k];
  }
}

__global__ void k_scan_bsum(int* __restrict__ bsum, int nb) {
  __shared__ int s[256];
  int t = threadIdx.x;
  int v = (t < nb) ? bsum[t] : 0;
  s[t] = v;
  __syncthreads();
  for (int off = 1; off < 256; off <<= 1) {
    int y = (t >= off) ? s[t - off] : 0;
    __syncthreads();
    s[t] += y;
    __syncthreads();
  }
  if (t < nb) bsum[t] = s[t] - v;  // exclusive
}

// rp[i] += bsum[chunk]; cursor = rp; dinv = rsqrt(deg+1)
__global__ void k_finish(int* __restrict__ rp, const int* __restrict__ bsum,
                         const int* __restrict__ cnt, int* __restrict__ cursor,
                         float* __restrict__ dinv, int n) {
  int i = blockIdx.x * blockDim.x + threadIdx.x;
  if (i <= n) {
    int r = rp[i] + bsum[i >> 10];
    rp[i] = r;
    if (i < n) {
      cursor[i] = r;
      dinv[i] = rsqrtf((float)cnt[i] + 1.0f);
    }
  }
}

__global__ void k_fill(const int* __restrict__ src, const int* __restrict__ dst,
                       int* __restrict__ cursor, int* __restrict__ csr_src, int e) {
  int i = blockIdx.x * blockDim.x + threadIdx.x;
  if (i < e) {
    int pos = atomicAdd(&cursor[dst[i]], 1);
    csr_src[pos] = src[i];
  }
}

// ======================= GEMM1: h1[n][64] = x[n][128] @ W1[64][128]^T =======================

__launch_bounds__(256)
__global__ void k_gemm1(const float* __restrict__ x, const float* __restrict__ W1,
                        float* __restrict__ h1, int n) {
  __shared__ float sW[64 * 128];
  int t = threadIdx.x;
  for (int idx = t; idx < 64 * 128; idx += 256) {
    int c = idx >> 7, k = idx & 127;
    sW[(c << 7) | (k ^ (((c >> 2) & 7) << 2))] = W1[idx];
  }
  __syncthreads();
  int r0 = blockIdx.x * 64;
  int tr = r0 + ((t >> 4) << 2);
  int tc = (t & 15) << 2;
  float acc[4][4] = {{0.f}};
  for (int kq = 0; kq < 32; ++kq) {
    float4 xv[4], wv[4];
#pragma unroll
    for (int i = 0; i < 4; ++i) {
      if (tr + i < n)
        xv[i] = *(const float4*)&x[(size_t)(tr + i) * 128 + (kq << 2)];
      else
        xv[i] = make_float4(0.f, 0.f, 0.f, 0.f);
    }
#pragma unroll
    for (int j = 0; j < 4; ++j) {
      int c = tc + j;
      wv[j] = *(const float4*)&sW[(c << 7) | ((kq << 2) ^ (((c >> 2) & 7) << 2))];
    }
#pragma unroll
    for (int i = 0; i < 4; ++i)
#pragma unroll
      for (int j = 0; j < 4; ++j) {
        acc[i][j] = fmaf(xv[i].x, wv[j].x, acc[i][j]);
        acc[i][j] = fmaf(xv[i].y, wv[j].y, acc[i][j]);
        acc[i][j] = fmaf(xv[i].z, wv[j].z, acc[i][j]);
        acc[i][j] = fmaf(xv[i].w, wv[j].w, acc[i][j]);
      }
  }
#pragma unroll
  for (int i = 0; i < 4; ++i) {
    int gr = tr + i;
    if (gr < n)
      *(float4*)&h1[(size_t)gr * 64 + tc] =
          make_float4(acc[i][0], acc[i][1], acc[i][2], acc[i][3]);
  }
}

// ======================= agg1: gather, 64 feats (wave per node) =======================
// agg1[v][f] = dinv[v] * ( dinv[v]*h1[v][f] + sum_{s in N(v)} dinv[s]*h1[s][f] )

__launch_bounds__(256)
__global__ void k_agg1(const float* __restrict__ h1, const float* __restrict__ dinv,
                       const int* __restrict__ rp, const int* __restrict__ csr_src,
                       float* __restrict__ agg1, int n) {
  int gid = blockIdx.x * 256 + threadIdx.x;
  int v = gid >> 6, f = gid & 63;
  if (v >= n) return;
  float dv = dinv[v];
  float acc = dv * h1[(size_t)v * 64 + f];
  int beg = rp[v], end = rp[v + 1];
  for (int j = beg; j < end; ++j) {
    int s = csr_src[j];
    acc += dinv[s] * h1[(size_t)s * 64 + f];
  }
  agg1[(size_t)v * 64 + f] = dv * acc;
}

// ======================= GEMM2: h2[n][32] = relu(agg1 + b1) @ W2[32][64]^T =======================

__launch_bounds__(256)
__global__ void k_gemm2(const float* __restrict__ agg1, const float* __restrict__ b1,
                        const float* __restrict__ W2, float* __restrict__ h2, int n) {
  __shared__ float sW[32 * 64];
  __shared__ float sb[64];
  int t = threadIdx.x;
  if (t < 64) sb[t] = b1[t];
  for (int idx = t; idx < 32 * 64; idx += 256) {
    int c = idx >> 6, k = idx & 63;
    sW[(c << 6) | (k ^ (((c >> 2) & 7) << 2))] = W2[idx];
  }
  __syncthreads();
  int r0 = blockIdx.x * 128;
  int tr = r0 + ((t >> 3) << 2);
  int tc = (t & 7) << 2;
  float acc[4][4] = {{0.f}};
  for (int kq = 0; kq < 16; ++kq) {
    float4 bv = *(const float4*)&sb[kq << 2];
    float4 xv[4], wv[4];
#pragma unroll
    for (int i = 0; i < 4; ++i) {
      if (tr + i < n) {
        float4 v = *(const float4*)&agg1[(size_t)(tr + i) * 64 + (kq << 2)];
        xv[i] = make_float4(fmaxf(v.x + bv.x, 0.f), fmaxf(v.y + bv.y, 0.f),
                            fmaxf(v.z + bv.z, 0.f), fmaxf(v.w + bv.w, 0.f));
      } else {
        xv[i] = make_float4(0.f, 0.f, 0.f, 0.f);
      }
    }
#pragma unroll
    for (int j = 0; j < 4; ++j) {
      int c = tc + j;
      wv[j] = *(const float4*)&sW[(c << 6) | ((kq << 2) ^ (((c >> 2) & 7) << 2))];
    }
#pragma unroll
    for (int i = 0; i < 4; ++i)
#pragma unroll
      for (int j = 0; j < 4; ++j) {
        acc[i][j] = fmaf(xv[i].x, wv[j].x, acc[i][j]);
        acc[i][j] = fmaf(xv[i].y, wv[j].y, acc[i][j]);
        acc[i][j] = fmaf(xv[i].z, wv[j].z, acc[i][j]);
        acc[i][j] = fmaf(xv[i].w, wv[j].w, acc[i][j]);
      }
  }
#pragma unroll
  for (int i = 0; i < 4; ++i) {
    int gr = tr + i;
    if (gr < n)
      *(float4*)&h2[(size_t)gr * 32 + tc] =
          make_float4(acc[i][0], acc[i][1], acc[i][2], acc[i][3]);
  }
}

// ======================= agg2: gather, 32 feats (half-wave per node) =======================
// out[v][f] = b2[f] + dinv[v] * ( dinv[v]*h2[v][f] + sum dinv[s]*h2[s][f] )

__launch_bounds__(256)
__global__ void k_agg2(const float* __restrict__ h2, const float* __restrict__ dinv,
                       const int* __restrict__ rp, const int* __restrict__ csr_src,
                       const float* __restrict__ b2, float* __restrict__ out, int n) {
  int gid = blockIdx.x * 256 + threadIdx.x;
  int v = gid >> 5, f = gid & 31;
  if (v >= n) return;
  float dv = dinv[v];
  float acc = dv * h2[(size_t)v * 32 + f];
  int beg = rp[v], end = rp[v + 1];
  for (int j = beg; j < end; ++j) {
    int s = csr_src[j];
    acc += dinv[s] * h2[(size_t)s * 32 + f];
  }
  out[(size_t)v * 32 + f] = fmaf(dv, acc, b2[f]);
}

// ======================= launcher =======================

extern "C" void kernel_launch(void* const* d_in, const int* in_sizes, int n_in,
                              void* d_out, int out_size, void* d_ws, size_t ws_size,
                              hipStream_t stream) {
  const float* x = (const float*)d_in[0];
  const int* ei = (const int*)d_in[1];
  const float* W1 = (const float*)d_in[2];
  const float* b1 = (const float*)d_in[3];
  const float* W2 = (const float*)d_in[4];
  const float* b2 = (const float*)d_in[5];
  float* out = (float*)d_out;

  const int n = in_sizes[0] / 128;  // 100000
  const int e = in_sizes[1] / 2;    // 1600000
  const int* src = ei;
  const int* dst = ei + e;

  // workspace layout (all 256B-aligned)
  char* base = (char*)d_ws;
  size_t off = 0;
  auto alloc = [&](size_t bytes) {
    char* p = base + off;
    off = (off + bytes + 255) & ~(size_t)255;
    return p;
  };
  int* cnt = (int*)alloc((size_t)n * 4);
  int* rp = (int*)alloc((size_t)(n + 1) * 4);
  int* cursor = (int*)alloc((size_t)n * 4);
  int* csr_src = (int*)alloc((size_t)e * 4);
  float* dinv = (float*)alloc((size_t)n * 4);
  int* bsum = (int*)alloc(1024 * 4);
  float* h1 = (float*)alloc((size_t)n * 64 * 4);
  float* agg1 = (float*)alloc((size_t)n * 64 * 4);
  float* h2 = (float*)alloc((size_t)n * 32 * 4);

  const int NC = (n + 1 + 1023) / 1024;  // scan chunks (covers index n)

  // CSR build
  k_zero<<<(n + THREADS - 1) / THREADS, THREADS, 0, stream>>>(cnt, n);
  k_count<<<(e + THREADS - 1) / THREADS, THREADS, 0, stream>>>(dst, cnt, e);
  k_scan_chunk<<<NC, 256, 0, stream>>>(cnt, rp, bsum, n);
  k_scan_bsum<<<1, 256, 0, stream>>>(bsum, NC);
  k_finish<<<(n + 1 + THREADS - 1) / THREADS, THREADS, 0, stream>>>(rp, bsum, cnt,
                                                                   cursor, dinv, n);
  k_fill<<<(e + THREADS - 1) / THREADS, THREADS, 0, stream>>>(src, dst, cursor,
                                                              csr_src, e);

  // layer 1
  k_gemm1<<<(n + 63) / 64, 256, 0, stream>>>(x, W1, h1, n);
  {
    long long total = (long long)n * 64;
    k_agg1<<<(int)((total + 255) / 256), 256, 0, stream>>>(h1, dinv, rp, csr_src,
                                                           agg1, n);
  }

  // layer 2
  k_gemm2<<<(n + 127) / 128, 256, 0, stream>>>(agg1, b1, W2, h2, n);
  {
    long long total = (long long)n * 32;
    k_agg2<<<(int)((total + 255) / 256), 256, 0, stream>>>(h2, dinv, rp, csr_src, b2,
                                                           out, n);
  }
}

// Round 3
// 469.738 us; speedup vs baseline: 1.7202x; 1.3071x over previous
//
#include <hip/hip_runtime.h>

#define THREADS 256

// ======================= CSR build =======================

__global__ void k_zero(int* __restrict__ cnt, int n) {
  int i = blockIdx.x * blockDim.x + threadIdx.x;
  if (i < n) cnt[i] = 0;
}

// zero row n of h1s (64 floats) and h2s (32 floats)
__global__ void k_zrow(float* __restrict__ h1s, float* __restrict__ h2s, int n) {
  int t = threadIdx.x;
  if (t < 64) h1s[(size_t)n * 64 + t] = 0.f;
  else if (t < 96) h2s[(size_t)n * 32 + (t - 64)] = 0.f;
}

__global__ void k_count(const int* __restrict__ dst, int* __restrict__ cnt, int e) {
  int i = blockIdx.x * blockDim.x + threadIdx.x;
  if (i < e) atomicAdd(&cnt[dst[i]], 1);
}

// chunk = 1024 counts per 256-thread block; exclusive scan within chunk.
__global__ void k_scan_chunk(const int* __restrict__ cnt, int* __restrict__ rp,
                             int* __restrict__ bsum, int n) {
  __shared__ int s[256];
  int b = blockIdx.x, t = threadIdx.x;
  int base = b * 1024 + t * 4;
  int v[4];
  int sum = 0;
#pragma unroll
  for (int k = 0; k < 4; ++k) {
    int i = base + k;
    v[k] = (i < n) ? cnt[i] : 0;
    sum += v[k];
  }
  s[t] = sum;
  __syncthreads();
  int mine = sum;
  for (int off = 1; off < 256; off <<= 1) {
    int y = (t >= off) ? s[t - off] : 0;
    __syncthreads();
    s[t] += y;
    __syncthreads();
  }
  int run = s[t] - mine;
  if (t == 255) bsum[b] = s[255];
#pragma unroll
  for (int k = 0; k < 4; ++k) {
    int i = base + k;
    if (i <= n) rp[i] = run;
    run += v[k];
  }
}

__global__ void k_scan_bsum(int* __restrict__ bsum, int nb) {
  __shared__ int s[256];
  int t = threadIdx.x;
  int v = (t < nb) ? bsum[t] : 0;
  s[t] = v;
  __syncthreads();
  for (int off = 1; off < 256; off <<= 1) {
    int y = (t >= off) ? s[t - off] : 0;
    __syncthreads();
    s[t] += y;
    __syncthreads();
  }
  if (t < nb) bsum[t] = s[t] - v;
}

__global__ void k_finish(int* __restrict__ rp, const int* __restrict__ bsum,
                         const int* __restrict__ cnt, int* __restrict__ cursor,
                         float* __restrict__ dinv, int n) {
  int i = blockIdx.x * blockDim.x + threadIdx.x;
  if (i <= n) {
    int r = rp[i] + bsum[i >> 10];
    rp[i] = r;
    if (i < n) {
      cursor[i] = r;
      dinv[i] = rsqrtf((float)cnt[i] + 1.0f);
    }
  }
}

__global__ void k_fill(const int* __restrict__ src, const int* __restrict__ dst,
                       int* __restrict__ cursor, int* __restrict__ csr_src, int e) {
  int i = blockIdx.x * blockDim.x + threadIdx.x;
  if (i < e) {
    int pos = atomicAdd(&cursor[dst[i]], 1);
    csr_src[pos] = src[i];
  }
}

// ======================= GEMM1: h1s[n][64] = dinv[r] * (x[n][128] @ W1^T) ==========

__launch_bounds__(256)
__global__ void k_gemm1(const float* __restrict__ x, const float* __restrict__ W1,
                        const float* __restrict__ dinv, float* __restrict__ h1s, int n) {
  __shared__ float sW[64 * 128];
  int t = threadIdx.x;
  for (int idx = t; idx < 64 * 128; idx += 256) {
    int c = idx >> 7, k = idx & 127;
    sW[(c << 7) | (k ^ (((c >> 2) & 7) << 2))] = W1[idx];
  }
  __syncthreads();
  int r0 = blockIdx.x * 64;
  int tr = r0 + ((t >> 4) << 2);
  int tc = (t & 15) << 2;
  float acc[4][4] = {{0.f}};
  for (int kq = 0; kq < 32; ++kq) {
    float4 xv[4], wv[4];
#pragma unroll
    for (int i = 0; i < 4; ++i) {
      if (tr + i < n)
        xv[i] = *(const float4*)&x[(size_t)(tr + i) * 128 + (kq << 2)];
      else
        xv[i] = make_float4(0.f, 0.f, 0.f, 0.f);
    }
#pragma unroll
    for (int j = 0; j < 4; ++j) {
      int c = tc + j;
      wv[j] = *(const float4*)&sW[(c << 7) | ((kq << 2) ^ (((c >> 2) & 7) << 2))];
    }
#pragma unroll
    for (int i = 0; i < 4; ++i)
#pragma unroll
      for (int j = 0; j < 4; ++j) {
        acc[i][j] = fmaf(xv[i].x, wv[j].x, acc[i][j]);
        acc[i][j] = fmaf(xv[i].y, wv[j].y, acc[i][j]);
        acc[i][j] = fmaf(xv[i].z, wv[j].z, acc[i][j]);
        acc[i][j] = fmaf(xv[i].w, wv[j].w, acc[i][j]);
      }
  }
#pragma unroll
  for (int i = 0; i < 4; ++i) {
    int gr = tr + i;
    if (gr < n) {
      float dv = dinv[gr];
      *(float4*)&h1s[(size_t)gr * 64 + tc] =
          make_float4(acc[i][0] * dv, acc[i][1] * dv, acc[i][2] * dv, acc[i][3] * dv);
    }
  }
}

// ======================= agg1: gather, 64 feats (wave per node), unroll 8 ==========
// agg1[v][f] = dinv[v] * ( h1s[v][f] + sum_{s in N(v)} h1s[s][f] )

__launch_bounds__(256)
__global__ void k_agg1(const float* __restrict__ h1s, const float* __restrict__ dinv,
                       const int* __restrict__ rp, const int* __restrict__ csr_src,
                       float* __restrict__ agg1, int n) {
  int gid = blockIdx.x * 256 + threadIdx.x;
  int v = gid >> 6, f = gid & 63;
  if (v >= n) return;
  int beg = rp[v], end = rp[v + 1];
  float a0 = h1s[(size_t)v * 64 + f];  // self term
  float a1 = 0.f, a2 = 0.f, a3 = 0.f, a4 = 0.f, a5 = 0.f, a6 = 0.f, a7 = 0.f;
  for (int j = beg; j < end; j += 8) {
    // csr_src padded by 8 ints; out-of-range edges redirect to zero row n
    int s0 = csr_src[j];
    int s1 = csr_src[j + 1];
    int s2 = csr_src[j + 2];
    int s3 = csr_src[j + 3];
    int s4 = csr_src[j + 4];
    int s5 = csr_src[j + 5];
    int s6 = csr_src[j + 6];
    int s7 = csr_src[j + 7];
    s1 = (j + 1 < end) ? s1 : n;
    s2 = (j + 2 < end) ? s2 : n;
    s3 = (j + 3 < end) ? s3 : n;
    s4 = (j + 4 < end) ? s4 : n;
    s5 = (j + 5 < end) ? s5 : n;
    s6 = (j + 6 < end) ? s6 : n;
    s7 = (j + 7 < end) ? s7 : n;
    a0 += h1s[(size_t)s0 * 64 + f];
    a1 += h1s[(size_t)s1 * 64 + f];
    a2 += h1s[(size_t)s2 * 64 + f];
    a3 += h1s[(size_t)s3 * 64 + f];
    a4 += h1s[(size_t)s4 * 64 + f];
    a5 += h1s[(size_t)s5 * 64 + f];
    a6 += h1s[(size_t)s6 * 64 + f];
    a7 += h1s[(size_t)s7 * 64 + f];
  }
  float acc = ((a0 + a1) + (a2 + a3)) + ((a4 + a5) + (a6 + a7));
  agg1[(size_t)v * 64 + f] = dinv[v] * acc;
}

// ======================= GEMM2: h2s = dinv[r] * (relu(agg1 + b1) @ W2^T) ==========

__launch_bounds__(256)
__global__ void k_gemm2(const float* __restrict__ agg1, const float* __restrict__ b1,
                        const float* __restrict__ W2, const float* __restrict__ dinv,
                        float* __restrict__ h2s, int n) {
  __shared__ float sW[32 * 64];
  __shared__ float sb[64];
  int t = threadIdx.x;
  if (t < 64) sb[t] = b1[t];
  for (int idx = t; idx < 32 * 64; idx += 256) {
    int c = idx >> 6, k = idx & 63;
    sW[(c << 6) | (k ^ (((c >> 2) & 7) << 2))] = W2[idx];
  }
  __syncthreads();
  int r0 = blockIdx.x * 128;
  int tr = r0 + ((t >> 3) << 2);
  int tc = (t & 7) << 2;
  float acc[4][4] = {{0.f}};
  for (int kq = 0; kq < 16; ++kq) {
    float4 bv = *(const float4*)&sb[kq << 2];
    float4 xv[4], wv[4];
#pragma unroll
    for (int i = 0; i < 4; ++i) {
      if (tr + i < n) {
        float4 v = *(const float4*)&agg1[(size_t)(tr + i) * 64 + (kq << 2)];
        xv[i] = make_float4(fmaxf(v.x + bv.x, 0.f), fmaxf(v.y + bv.y, 0.f),
                            fmaxf(v.z + bv.z, 0.f), fmaxf(v.w + bv.w, 0.f));
      } else {
        xv[i] = make_float4(0.f, 0.f, 0.f, 0.f);
      }
    }
#pragma unroll
    for (int j = 0; j < 4; ++j) {
      int c = tc + j;
      wv[j] = *(const float4*)&sW[(c << 6) | ((kq << 2) ^ (((c >> 2) & 7) << 2))];
    }
#pragma unroll
    for (int i = 0; i < 4; ++i)
#pragma unroll
      for (int j = 0; j < 4; ++j) {
        acc[i][j] = fmaf(xv[i].x, wv[j].x, acc[i][j]);
        acc[i][j] = fmaf(xv[i].y, wv[j].y, acc[i][j]);
        acc[i][j] = fmaf(xv[i].z, wv[j].z, acc[i][j]);
        acc[i][j] = fmaf(xv[i].w, wv[j].w, acc[i][j]);
      }
  }
#pragma unroll
  for (int i = 0; i < 4; ++i) {
    int gr = tr + i;
    if (gr < n) {
      float dv = dinv[gr];
      *(float4*)&h2s[(size_t)gr * 32 + tc] =
          make_float4(acc[i][0] * dv, acc[i][1] * dv, acc[i][2] * dv, acc[i][3] * dv);
    }
  }
}

// ======================= agg2: gather, 32 feats (half-wave per node), unroll 8 =====
// out[v][f] = b2[f] + dinv[v] * ( h2s[v][f] + sum h2s[s][f] )

__launch_bounds__(256)
__global__ void k_agg2(const float* __restrict__ h2s, const float* __restrict__ dinv,
                       const int* __restrict__ rp, const int* __restrict__ csr_src,
                       const float* __restrict__ b2, float* __restrict__ out, int n) {
  int gid = blockIdx.x * 256 + threadIdx.x;
  int v = gid >> 5, f = gid & 31;
  if (v >= n) return;
  int beg = rp[v], end = rp[v + 1];
  float a0 = h2s[(size_t)v * 32 + f];  // self term
  float a1 = 0.f, a2 = 0.f, a3 = 0.f, a4 = 0.f, a5 = 0.f, a6 = 0.f, a7 = 0.f;
  for (int j = beg; j < end; j += 8) {
    int s0 = csr_src[j];
    int s1 = csr_src[j + 1];
    int s2 = csr_src[j + 2];
    int s3 = csr_src[j + 3];
    int s4 = csr_src[j + 4];
    int s5 = csr_src[j + 5];
    int s6 = csr_src[j + 6];
    int s7 = csr_src[j + 7];
    s1 = (j + 1 < end) ? s1 : n;
    s2 = (j + 2 < end) ? s2 : n;
    s3 = (j + 3 < end) ? s3 : n;
    s4 = (j + 4 < end) ? s4 : n;
    s5 = (j + 5 < end) ? s5 : n;
    s6 = (j + 6 < end) ? s6 : n;
    s7 = (j + 7 < end) ? s7 : n;
    a0 += h2s[(size_t)s0 * 32 + f];
    a1 += h2s[(size_t)s1 * 32 + f];
    a2 += h2s[(size_t)s2 * 32 + f];
    a3 += h2s[(size_t)s3 * 32 + f];
    a4 += h2s[(size_t)s4 * 32 + f];
    a5 += h2s[(size_t)s5 * 32 + f];
    a6 += h2s[(size_t)s6 * 32 + f];
    a7 += h2s[(size_t)s7 * 32 + f];
  }
  float acc = ((a0 + a1) + (a2 + a3)) + ((a4 + a5) + (a6 + a7));
  out[(size_t)v * 32 + f] = fmaf(dinv[v], acc, b2[f]);
}

// ======================= launcher =======================

extern "C" void kernel_launch(void* const* d_in, const int* in_sizes, int n_in,
                              void* d_out, int out_size, void* d_ws, size_t ws_size,
                              hipStream_t stream) {
  const float* x = (const float*)d_in[0];
  const int* ei = (const int*)d_in[1];
  const float* W1 = (const float*)d_in[2];
  const float* b1 = (const float*)d_in[3];
  const float* W2 = (const float*)d_in[4];
  const float* b2 = (const float*)d_in[5];
  float* out = (float*)d_out;

  const int n = in_sizes[0] / 128;  // 100000
  const int e = in_sizes[1] / 2;    // 1600000
  const int* src = ei;
  const int* dst = ei + e;

  char* base = (char*)d_ws;
  size_t off = 0;
  auto alloc = [&](size_t bytes) {
    char* p = base + off;
    off = (off + bytes + 255) & ~(size_t)255;
    return p;
  };
  int* cnt = (int*)alloc((size_t)n * 4);
  int* rp = (int*)alloc((size_t)(n + 1) * 4);
  int* cursor = (int*)alloc((size_t)n * 4);
  int* csr_src = (int*)alloc((size_t)(e + 8) * 4);  // +8 pad for unrolled reads
  float* dinv = (float*)alloc((size_t)n * 4);
  int* bsum = (int*)alloc(1024 * 4);
  float* h1s = (float*)alloc((size_t)(n + 1) * 64 * 4);  // +1 zero row
  float* agg1 = (float*)alloc((size_t)n * 64 * 4);
  float* h2s = (float*)alloc((size_t)(n + 1) * 32 * 4);  // +1 zero row

  const int NC = (n + 1 + 1023) / 1024;

  // CSR build
  k_zero<<<(n + THREADS - 1) / THREADS, THREADS, 0, stream>>>(cnt, n);
  k_zrow<<<1, 128, 0, stream>>>(h1s, h2s, n);
  k_count<<<(e + THREADS - 1) / THREADS, THREADS, 0, stream>>>(dst, cnt, e);
  k_scan_chunk<<<NC, 256, 0, stream>>>(cnt, rp, bsum, n);
  k_scan_bsum<<<1, 256, 0, stream>>>(bsum, NC);
  k_finish<<<(n + 1 + THREADS - 1) / THREADS, THREADS, 0, stream>>>(rp, bsum, cnt,
                                                                   cursor, dinv, n);
  k_fill<<<(e + THREADS - 1) / THREADS, THREADS, 0, stream>>>(src, dst, cursor,
                                                              csr_src, e);

  // layer 1
  k_gemm1<<<(n + 63) / 64, 256, 0, stream>>>(x, W1, dinv, h1s, n);
  {
    long long total = (long long)n * 64;
    k_agg1<<<(int)((total + 255) / 256), 256, 0, stream>>>(h1s, dinv, rp, csr_src,
                                                           agg1, n);
  }

  // layer 2
  k_gemm2<<<(n + 127) / 128, 256, 0, stream>>>(agg1, b1, W2, dinv, h2s, n);
  {
    long long total = (long long)n * 32;
    k_agg2<<<(int)((total + 255) / 256), 256, 0, stream>>>(h2s, dinv, rp, csr_src, b2,
                                                           out, n);
  }
}

// Round 4
// 341.955 us; speedup vs baseline: 2.3629x; 1.3737x over previous
//
#include <hip/hip_runtime.h>

#define THREADS 256
#define G1 256          // partition blocks
#define MAXNB 4096      // max coarse buckets (n <= 512k)

// ======================= scan machinery (generic, chunk=1024) =======================

// exclusive scan of cnt[0..m) into rp[0..m] (rp[m] = partial, fixed by add-back)
__global__ void k_scan_chunk(const int* __restrict__ cnt, int* __restrict__ rp,
                             int* __restrict__ bsum, int m) {
  __shared__ int s[256];
  int b = blockIdx.x, t = threadIdx.x;
  int base = b * 1024 + t * 4;
  int v[4];
  int sum = 0;
#pragma unroll
  for (int k = 0; k < 4; ++k) {
    int i = base + k;
    v[k] = (i < m) ? cnt[i] : 0;
    sum += v[k];
  }
  s[t] = sum;
  __syncthreads();
  int mine = sum;
  for (int off = 1; off < 256; off <<= 1) {
    int y = (t >= off) ? s[t - off] : 0;
    __syncthreads();
    s[t] += y;
    __syncthreads();
  }
  int run = s[t] - mine;
  if (t == 255) bsum[b] = s[255];
#pragma unroll
  for (int k = 0; k < 4; ++k) {
    int i = base + k;
    if (i <= m) rp[i] = run;
    run += v[k];
  }
}

__global__ void k_scan_bsum(int* __restrict__ bsum, int nb) {
  __shared__ int s[256];
  int t = threadIdx.x;
  int v = (t < nb) ? bsum[t] : 0;
  s[t] = v;
  __syncthreads();
  for (int off = 1; off < 256; off <<= 1) {
    int y = (t >= off) ? s[t - off] : 0;
    __syncthreads();
    s[t] += y;
    __syncthreads();
  }
  if (t < nb) bsum[t] = s[t] - v;
}

__global__ void k_add(int* __restrict__ a, const int* __restrict__ bsum, int m) {
  int i = blockIdx.x * blockDim.x + threadIdx.x;
  if (i < m) a[i] += bsum[i >> 10];
}

// ======================= misc init =======================

// zero row n of h1s (64 floats) and h2s (32 floats)
__global__ void k_zrow(float* __restrict__ h1s, float* __restrict__ h2s, int n) {
  int t = threadIdx.x;
  if (t < 64) h1s[(size_t)n * 64 + t] = 0.f;
  else if (t < 96) h2s[(size_t)n * 32 + (t - 64)] = 0.f;
}

// ======================= CSR build: two-phase partition, LDS atomics only ===========

// P1a: per-block coarse histogram (bucket = dst>>7), write C[bucket][block]
__launch_bounds__(256)
__global__ void k_pcount(const int* __restrict__ dst, int* __restrict__ C, int e,
                         int NB, int chunk) {
  __shared__ int h[MAXNB];
  int blk = blockIdx.x, t = threadIdx.x;
  for (int i = t; i < NB; i += 256) h[i] = 0;
  __syncthreads();
  int beg = blk * chunk;
  int stop = min(e, beg + chunk);
  for (int j = beg + t; j < stop; j += 256) atomicAdd(&h[dst[j] >> 7], 1);
  __syncthreads();
  for (int i = t; i < NB; i += 256) C[i * G1 + blk] = h[i];
}

// P1b: scatter edges into bucket regions; pack (src<<7)|(dst&127)
__launch_bounds__(256)
__global__ void k_partition(const int* __restrict__ src, const int* __restrict__ dst,
                            const int* __restrict__ Cs, int* __restrict__ bpack, int e,
                            int NB, int chunk) {
  __shared__ int cur[MAXNB];
  int blk = blockIdx.x, t = threadIdx.x;
  for (int i = t; i < NB; i += 256) cur[i] = Cs[i * G1 + blk];
  __syncthreads();
  int beg = blk * chunk;
  int stop = min(e, beg + chunk);
  for (int j = beg + t; j < stop; j += 256) {
    int d = dst[j];
    int b = d >> 7;
    int pos = atomicAdd(&cur[b], 1);
    bpack[pos] = (src[j] << 7) | (d & 127);
  }
}

// P2: per-bucket CSR: count 128 nodes in LDS, LDS scan -> rp/dinv, fill csr_src
__launch_bounds__(256)
__global__ void k_bucket_csr(const int* __restrict__ bpack, const int* __restrict__ Cs,
                             int* __restrict__ rp, float* __restrict__ dinv,
                             int* __restrict__ csr_src, int n, int e, int NB) {
  __shared__ int cl[128];
  __shared__ int cur[128];
  int blk = blockIdx.x, t = threadIdx.x;
  int base = Cs[blk * G1];
  int end = (blk == NB - 1) ? e : Cs[(blk + 1) * G1];
  if (t < 128) cl[t] = 0;
  __syncthreads();
  for (int j = base + t; j < end; j += 256) atomicAdd(&cl[bpack[j] & 127], 1);
  __syncthreads();
  int own = (t < 128) ? cl[t] : 0;
  // inclusive scan over cl[0..128)
  for (int off = 1; off < 128; off <<= 1) {
    int y = (t >= off && t < 128) ? cl[t - off] : 0;
    __syncthreads();
    if (t < 128) cl[t] += y;
    __syncthreads();
  }
  if (t < 128) {
    int excl = cl[t] - own;
    int v = (blk << 7) + t;
    if (v < n) {
      rp[v] = base + excl;
      dinv[v] = rsqrtf((float)own + 1.0f);
    }
    cur[t] = base + excl;
  }
  __syncthreads();
  for (int j = base + t; j < end; j += 256) {
    int p = bpack[j];
    int pos = atomicAdd(&cur[p & 127], 1);
    csr_src[pos] = p >> 7;
  }
  if (blk == 0 && t == 0) rp[n] = e;
}

// ======================= GEMM1: h1s[n][64] = dinv[r] * (x[n][128] @ W1^T) ==========

__launch_bounds__(256)
__global__ void k_gemm1(const float* __restrict__ x, const float* __restrict__ W1,
                        const float* __restrict__ dinv, float* __restrict__ h1s, int n) {
  __shared__ float sW[64 * 128];
  int t = threadIdx.x;
  for (int idx = t; idx < 64 * 128; idx += 256) {
    int c = idx >> 7, k = idx & 127;
    sW[(c << 7) | (k ^ (((c >> 2) & 7) << 2))] = W1[idx];
  }
  __syncthreads();
  int r0 = blockIdx.x * 64;
  int tr = r0 + ((t >> 4) << 2);
  int tc = (t & 15) << 2;
  float acc[4][4] = {{0.f}};
  for (int kq = 0; kq < 32; ++kq) {
    float4 xv[4], wv[4];
#pragma unroll
    for (int i = 0; i < 4; ++i) {
      if (tr + i < n)
        xv[i] = *(const float4*)&x[(size_t)(tr + i) * 128 + (kq << 2)];
      else
        xv[i] = make_float4(0.f, 0.f, 0.f, 0.f);
    }
#pragma unroll
    for (int j = 0; j < 4; ++j) {
      int c = tc + j;
      wv[j] = *(const float4*)&sW[(c << 7) | ((kq << 2) ^ (((c >> 2) & 7) << 2))];
    }
#pragma unroll
    for (int i = 0; i < 4; ++i)
#pragma unroll
      for (int j = 0; j < 4; ++j) {
        acc[i][j] = fmaf(xv[i].x, wv[j].x, acc[i][j]);
        acc[i][j] = fmaf(xv[i].y, wv[j].y, acc[i][j]);
        acc[i][j] = fmaf(xv[i].z, wv[j].z, acc[i][j]);
        acc[i][j] = fmaf(xv[i].w, wv[j].w, acc[i][j]);
      }
  }
#pragma unroll
  for (int i = 0; i < 4; ++i) {
    int gr = tr + i;
    if (gr < n) {
      float dv = dinv[gr];
      *(float4*)&h1s[(size_t)gr * 64 + tc] =
          make_float4(acc[i][0] * dv, acc[i][1] * dv, acc[i][2] * dv, acc[i][3] * dv);
    }
  }
}

// ======================= agg1: gather, 64 feats (wave per node), unroll 8 ==========

__launch_bounds__(256)
__global__ void k_agg1(const float* __restrict__ h1s, const float* __restrict__ dinv,
                       const int* __restrict__ rp, const int* __restrict__ csr_src,
                       float* __restrict__ agg1, int n) {
  int gid = blockIdx.x * 256 + threadIdx.x;
  int v = gid >> 6, f = gid & 63;
  if (v >= n) return;
  int beg = rp[v], end = rp[v + 1];
  float a0 = h1s[(size_t)v * 64 + f];  // self term
  float a1 = 0.f, a2 = 0.f, a3 = 0.f, a4 = 0.f, a5 = 0.f, a6 = 0.f, a7 = 0.f;
  for (int j = beg; j < end; j += 8) {
    int s0 = csr_src[j];
    int s1 = csr_src[j + 1];
    int s2 = csr_src[j + 2];
    int s3 = csr_src[j + 3];
    int s4 = csr_src[j + 4];
    int s5 = csr_src[j + 5];
    int s6 = csr_src[j + 6];
    int s7 = csr_src[j + 7];
    s1 = (j + 1 < end) ? s1 : n;
    s2 = (j + 2 < end) ? s2 : n;
    s3 = (j + 3 < end) ? s3 : n;
    s4 = (j + 4 < end) ? s4 : n;
    s5 = (j + 5 < end) ? s5 : n;
    s6 = (j + 6 < end) ? s6 : n;
    s7 = (j + 7 < end) ? s7 : n;
    a0 += h1s[(size_t)s0 * 64 + f];
    a1 += h1s[(size_t)s1 * 64 + f];
    a2 += h1s[(size_t)s2 * 64 + f];
    a3 += h1s[(size_t)s3 * 64 + f];
    a4 += h1s[(size_t)s4 * 64 + f];
    a5 += h1s[(size_t)s5 * 64 + f];
    a6 += h1s[(size_t)s6 * 64 + f];
    a7 += h1s[(size_t)s7 * 64 + f];
  }
  float acc = ((a0 + a1) + (a2 + a3)) + ((a4 + a5) + (a6 + a7));
  agg1[(size_t)v * 64 + f] = dinv[v] * acc;
}

// ======================= GEMM2: h2s = dinv[r] * (relu(agg1 + b1) @ W2^T) ==========

__launch_bounds__(256)
__global__ void k_gemm2(const float* __restrict__ agg1, const float* __restrict__ b1,
                        const float* __restrict__ W2, const float* __restrict__ dinv,
                        float* __restrict__ h2s, int n) {
  __shared__ float sW[32 * 64];
  __shared__ float sb[64];
  int t = threadIdx.x;
  if (t < 64) sb[t] = b1[t];
  for (int idx = t; idx < 32 * 64; idx += 256) {
    int c = idx >> 6, k = idx & 63;
    sW[(c << 6) | (k ^ (((c >> 2) & 7) << 2))] = W2[idx];
  }
  __syncthreads();
  int r0 = blockIdx.x * 128;
  int tr = r0 + ((t >> 3) << 2);
  int tc = (t & 7) << 2;
  float acc[4][4] = {{0.f}};
  for (int kq = 0; kq < 16; ++kq) {
    float4 bv = *(const float4*)&sb[kq << 2];
    float4 xv[4], wv[4];
#pragma unroll
    for (int i = 0; i < 4; ++i) {
      if (tr + i < n) {
        float4 v = *(const float4*)&agg1[(size_t)(tr + i) * 64 + (kq << 2)];
        xv[i] = make_float4(fmaxf(v.x + bv.x, 0.f), fmaxf(v.y + bv.y, 0.f),
                            fmaxf(v.z + bv.z, 0.f), fmaxf(v.w + bv.w, 0.f));
      } else {
        xv[i] = make_float4(0.f, 0.f, 0.f, 0.f);
      }
    }
#pragma unroll
    for (int j = 0; j < 4; ++j) {
      int c = tc + j;
      wv[j] = *(const float4*)&sW[(c << 6) | ((kq << 2) ^ (((c >> 2) & 7) << 2))];
    }
#pragma unroll
    for (int i = 0; i < 4; ++i)
#pragma unroll
      for (int j = 0; j < 4; ++j) {
        acc[i][j] = fmaf(xv[i].x, wv[j].x, acc[i][j]);
        acc[i][j] = fmaf(xv[i].y, wv[j].y, acc[i][j]);
        acc[i][j] = fmaf(xv[i].z, wv[j].z, acc[i][j]);
        acc[i][j] = fmaf(xv[i].w, wv[j].w, acc[i][j]);
      }
  }
#pragma unroll
  for (int i = 0; i < 4; ++i) {
    int gr = tr + i;
    if (gr < n) {
      float dv = dinv[gr];
      *(float4*)&h2s[(size_t)gr * 32 + tc] =
          make_float4(acc[i][0] * dv, acc[i][1] * dv, acc[i][2] * dv, acc[i][3] * dv);
    }
  }
}

// ======================= agg2: gather, 32 feats (half-wave per node), unroll 8 =====

__launch_bounds__(256)
__global__ void k_agg2(const float* __restrict__ h2s, const float* __restrict__ dinv,
                       const int* __restrict__ rp, const int* __restrict__ csr_src,
                       const float* __restrict__ b2, float* __restrict__ out, int n) {
  int gid = blockIdx.x * 256 + threadIdx.x;
  int v = gid >> 5, f = gid & 31;
  if (v >= n) return;
  int beg = rp[v], end = rp[v + 1];
  float a0 = h2s[(size_t)v * 32 + f];  // self term
  float a1 = 0.f, a2 = 0.f, a3 = 0.f, a4 = 0.f, a5 = 0.f, a6 = 0.f, a7 = 0.f;
  for (int j = beg; j < end; j += 8) {
    int s0 = csr_src[j];
    int s1 = csr_src[j + 1];
    int s2 = csr_src[j + 2];
    int s3 = csr_src[j + 3];
    int s4 = csr_src[j + 4];
    int s5 = csr_src[j + 5];
    int s6 = csr_src[j + 6];
    int s7 = csr_src[j + 7];
    s1 = (j + 1 < end) ? s1 : n;
    s2 = (j + 2 < end) ? s2 : n;
    s3 = (j + 3 < end) ? s3 : n;
    s4 = (j + 4 < end) ? s4 : n;
    s5 = (j + 5 < end) ? s5 : n;
    s6 = (j + 6 < end) ? s6 : n;
    s7 = (j + 7 < end) ? s7 : n;
    a0 += h2s[(size_t)s0 * 32 + f];
    a1 += h2s[(size_t)s1 * 32 + f];
    a2 += h2s[(size_t)s2 * 32 + f];
    a3 += h2s[(size_t)s3 * 32 + f];
    a4 += h2s[(size_t)s4 * 32 + f];
    a5 += h2s[(size_t)s5 * 32 + f];
    a6 += h2s[(size_t)s6 * 32 + f];
    a7 += h2s[(size_t)s7 * 32 + f];
  }
  float acc = ((a0 + a1) + (a2 + a3)) + ((a4 + a5) + (a6 + a7));
  out[(size_t)v * 32 + f] = fmaf(dinv[v], acc, b2[f]);
}

// ======================= launcher =======================

extern "C" void kernel_launch(void* const* d_in, const int* in_sizes, int n_in,
                              void* d_out, int out_size, void* d_ws, size_t ws_size,
                              hipStream_t stream) {
  const float* x = (const float*)d_in[0];
  const int* ei = (const int*)d_in[1];
  const float* W1 = (const float*)d_in[2];
  const float* b1 = (const float*)d_in[3];
  const float* W2 = (const float*)d_in[4];
  const float* b2 = (const float*)d_in[5];
  float* out = (float*)d_out;

  const int n = in_sizes[0] / 128;  // 100000
  const int e = in_sizes[1] / 2;    // 1600000
  const int* src = ei;
  const int* dst = ei + e;

  const int NB = (n + 127) >> 7;          // coarse buckets (782)
  const int m = NB * G1;                  // count-matrix size
  const int chunk = (e + G1 - 1) / G1;    // edges per partition block
  const int NC = (m + 1 + 1023) / 1024;   // scan chunks

  char* base = (char*)d_ws;
  size_t off = 0;
  auto alloc = [&](size_t bytes) {
    char* p = base + off;
    off = (off + bytes + 255) & ~(size_t)255;
    return p;
  };
  int* C = (int*)alloc((size_t)m * 4);
  int* Cs = (int*)alloc((size_t)(m + 1) * 4);
  int* bsum = (int*)alloc(1024 * 4);
  int* bpack = (int*)alloc((size_t)e * 4);
  int* rp = (int*)alloc((size_t)(n + 1) * 4);
  int* csr_src = (int*)alloc((size_t)(e + 8) * 4);  // +8 pad for unrolled reads
  float* dinv = (float*)alloc((size_t)n * 4);
  float* h1s = (float*)alloc((size_t)(n + 1) * 64 * 4);  // +1 zero row
  float* agg1 = (float*)alloc((size_t)n * 64 * 4);
  float* h2s = (float*)alloc((size_t)(n + 1) * 32 * 4);  // +1 zero row

  // CSR build (no global atomics)
  k_zrow<<<1, 128, 0, stream>>>(h1s, h2s, n);
  k_pcount<<<G1, 256, 0, stream>>>(dst, C, e, NB, chunk);
  k_scan_chunk<<<NC, 256, 0, stream>>>(C, Cs, bsum, m);
  k_scan_bsum<<<1, 256, 0, stream>>>(bsum, NC);
  k_add<<<(m + 255) / 256, 256, 0, stream>>>(Cs, bsum, m);
  k_partition<<<G1, 256, 0, stream>>>(src, dst, Cs, bpack, e, NB, chunk);
  k_bucket_csr<<<NB, 256, 0, stream>>>(bpack, Cs, rp, dinv, csr_src, n, e, NB);

  // layer 1
  k_gemm1<<<(n + 63) / 64, 256, 0, stream>>>(x, W1, dinv, h1s, n);
  {
    long long total = (long long)n * 64;
    k_agg1<<<(int)((total + 255) / 256), 256, 0, stream>>>(h1s, dinv, rp, csr_src,
                                                           agg1, n);
  }

  // layer 2
  k_gemm2<<<(n + 127) / 128, 256, 0, stream>>>(agg1, b1, W2, dinv, h2s, n);
  {
    long long total = (long long)n * 32;
    k_agg2<<<(int)((total + 255) / 256), 256, 0, stream>>>(h2s, dinv, rp, csr_src, b2,
                                                           out, n);
  }
}

// Round 5
// 306.277 us; speedup vs baseline: 2.6382x; 1.1165x over previous
//
#include <hip/hip_runtime.h>

#define THREADS 256
#define G1 256          // partition blocks
#define MAXNB 4096      // max coarse buckets (n <= 512k)

// ======================= scan machinery (generic, chunk=1024) =======================

__global__ void k_scan_chunk(const int* __restrict__ cnt, int* __restrict__ rp,
                             int* __restrict__ bsum, int m) {
  __shared__ int s[256];
  int b = blockIdx.x, t = threadIdx.x;
  int base = b * 1024 + t * 4;
  int v[4];
  int sum = 0;
#pragma unroll
  for (int k = 0; k < 4; ++k) {
    int i = base + k;
    v[k] = (i < m) ? cnt[i] : 0;
    sum += v[k];
  }
  s[t] = sum;
  __syncthreads();
  int mine = sum;
  for (int off = 1; off < 256; off <<= 1) {
    int y = (t >= off) ? s[t - off] : 0;
    __syncthreads();
    s[t] += y;
    __syncthreads();
  }
  int run = s[t] - mine;
  if (t == 255) bsum[b] = s[255];
#pragma unroll
  for (int k = 0; k < 4; ++k) {
    int i = base + k;
    if (i <= m) rp[i] = run;
    run += v[k];
  }
}

__global__ void k_scan_bsum(int* __restrict__ bsum, int nb) {
  __shared__ int s[256];
  int t = threadIdx.x;
  int v = (t < nb) ? bsum[t] : 0;
  s[t] = v;
  __syncthreads();
  for (int off = 1; off < 256; off <<= 1) {
    int y = (t >= off) ? s[t - off] : 0;
    __syncthreads();
    s[t] += y;
    __syncthreads();
  }
  if (t < nb) bsum[t] = s[t] - v;
}

__global__ void k_add(int* __restrict__ a, const int* __restrict__ bsum, int m) {
  int i = blockIdx.x * blockDim.x + threadIdx.x;
  if (i < m) a[i] += bsum[i >> 10];
}

// ======================= misc init =======================

__global__ void k_zrow(float* __restrict__ h1s, float* __restrict__ h2s, int n) {
  int t = threadIdx.x;
  if (t < 64) h1s[(size_t)n * 64 + t] = 0.f;
  else if (t < 96) h2s[(size_t)n * 32 + (t - 64)] = 0.f;
}

// ======================= CSR build: two-phase partition, LDS atomics only ===========

__launch_bounds__(256)
__global__ void k_pcount(const int* __restrict__ dst, int* __restrict__ C, int e,
                         int NB, int chunk) {
  __shared__ int h[MAXNB];
  int blk = blockIdx.x, t = threadIdx.x;
  for (int i = t; i < NB; i += 256) h[i] = 0;
  __syncthreads();
  int beg = blk * chunk;
  int stop = min(e, beg + chunk);
  for (int j = beg + t; j < stop; j += 256) atomicAdd(&h[dst[j] >> 7], 1);
  __syncthreads();
  for (int i = t; i < NB; i += 256) C[i * G1 + blk] = h[i];
}

__launch_bounds__(256)
__global__ void k_partition(const int* __restrict__ src, const int* __restrict__ dst,
                            const int* __restrict__ Cs, int* __restrict__ bpack, int e,
                            int NB, int chunk) {
  __shared__ int cur[MAXNB];
  int blk = blockIdx.x, t = threadIdx.x;
  for (int i = t; i < NB; i += 256) cur[i] = Cs[i * G1 + blk];
  __syncthreads();
  int beg = blk * chunk;
  int stop = min(e, beg + chunk);
  for (int j = beg + t; j < stop; j += 256) {
    int d = dst[j];
    int b = d >> 7;
    int pos = atomicAdd(&cur[b], 1);
    bpack[pos] = (src[j] << 7) | (d & 127);
  }
}

__launch_bounds__(256)
__global__ void k_bucket_csr(const int* __restrict__ bpack, const int* __restrict__ Cs,
                             int* __restrict__ rp, float* __restrict__ dinv,
                             int* __restrict__ csr_src, int n, int e, int NB) {
  __shared__ int cl[128];
  __shared__ int cur[128];
  int blk = blockIdx.x, t = threadIdx.x;
  int base = Cs[blk * G1];
  int end = (blk == NB - 1) ? e : Cs[(blk + 1) * G1];
  if (t < 128) cl[t] = 0;
  __syncthreads();
  for (int j = base + t; j < end; j += 256) atomicAdd(&cl[bpack[j] & 127], 1);
  __syncthreads();
  int own = (t < 128) ? cl[t] : 0;
  for (int off = 1; off < 128; off <<= 1) {
    int y = (t >= off && t < 128) ? cl[t - off] : 0;
    __syncthreads();
    if (t < 128) cl[t] += y;
    __syncthreads();
  }
  if (t < 128) {
    int excl = cl[t] - own;
    int v = (blk << 7) + t;
    if (v < n) {
      rp[v] = base + excl;
      dinv[v] = rsqrtf((float)own + 1.0f);
    }
    cur[t] = base + excl;
  }
  __syncthreads();
  for (int j = base + t; j < end; j += 256) {
    int p = bpack[j];
    int pos = atomicAdd(&cur[p & 127], 1);
    csr_src[pos] = p >> 7;
  }
  if (blk == 0 && t == 0) rp[n] = e;
}

// ======================= GEMM1: h1s[n][64] = dinv[r] * (x[n][128] @ W1^T) ==========
// 128 rows/block. W1 (64x128) and x k-chunks (128x32) in LDS, both in float4
// units with XOR bank-quad swizzle. Thread t: 4 rows (rg=t>>3), 8 cols (cg=t&7).
// Per k4-step: 4+8 ds_read_b128, each hitting 8 (x) / 8 (W) distinct bank quads.

__launch_bounds__(256)
__global__ void k_gemm1(const float* __restrict__ x, const float* __restrict__ W1,
                        const float* __restrict__ dinv, float* __restrict__ h1s, int n) {
  __shared__ float4 sW4[64 * 32];   // 32 KB, full K
  __shared__ float4 sX4[128 * 8];   // 16 KB, K-chunk of 32
  int t = threadIdx.x;
  const float4* W14 = (const float4*)W1;
  const float4* x4 = (const float4*)x;
  // stage W1 once: row c has 32 f4; slot m stored at m ^ ((c>>3)&7)
#pragma unroll
  for (int p = 0; p < 8; ++p) {
    int q = t + 256 * p;
    int c = q >> 5, m = q & 31;
    sW4[c * 32 + (m ^ ((c >> 3) & 7))] = W14[c * 32 + m];
  }
  int cg = t & 7;        // col group: cols cg*8 .. cg*8+7
  int rg = t >> 3;       // row group: rows rg*4 .. rg*4+3 (0..31)
  int rbase = blockIdx.x * 128;
  int r0 = rbase + rg * 4;
  float acc[4][8] = {{0.f}};
  for (int ci = 0; ci < 4; ++ci) {
    __syncthreads();
    // stage x chunk: 128 rows x 8 f4, coalesced 128B per row
#pragma unroll
    for (int p = 0; p < 4; ++p) {
      int q = t + 256 * p;
      int r = q >> 3, s = q & 7;
      int gr = rbase + r;
      float4 v = (gr < n) ? x4[(size_t)gr * 32 + ci * 8 + s]
                          : make_float4(0.f, 0.f, 0.f, 0.f);
      sX4[r * 8 + (s ^ ((r >> 2) & 7))] = v;
    }
    __syncthreads();
#pragma unroll
    for (int k4 = 0; k4 < 8; ++k4) {
      int kf4 = ci * 8 + k4;
      float4 xv[4], wv[8];
#pragma unroll
      for (int i = 0; i < 4; ++i)
        xv[i] = sX4[(rg * 4 + i) * 8 + (k4 ^ (rg & 7))];
#pragma unroll
      for (int j = 0; j < 8; ++j)
        wv[j] = sW4[(cg * 8 + j) * 32 + (kf4 ^ cg)];
#pragma unroll
      for (int i = 0; i < 4; ++i)
#pragma unroll
        for (int j = 0; j < 8; ++j) {
          acc[i][j] = fmaf(xv[i].x, wv[j].x, acc[i][j]);
          acc[i][j] = fmaf(xv[i].y, wv[j].y, acc[i][j]);
          acc[i][j] = fmaf(xv[i].z, wv[j].z, acc[i][j]);
          acc[i][j] = fmaf(xv[i].w, wv[j].w, acc[i][j]);
        }
    }
  }
  // epilogue: scale by dinv[row], store 2 f4 per row (h1s row = 16 f4)
  float4* h1s4 = (float4*)h1s;
#pragma unroll
  for (int i = 0; i < 4; ++i) {
    int gr = r0 + i;
    if (gr < n) {
      float dv = dinv[gr];
      float4 o0 = make_float4(acc[i][0] * dv, acc[i][1] * dv, acc[i][2] * dv,
                              acc[i][3] * dv);
      float4 o1 = make_float4(acc[i][4] * dv, acc[i][5] * dv, acc[i][6] * dv,
                              acc[i][7] * dv);
      h1s4[(size_t)gr * 16 + cg * 2] = o0;
      h1s4[(size_t)gr * 16 + cg * 2 + 1] = o1;
    }
  }
}

// ======================= agg1: gather, 64 feats (wave per node), unroll 8 ==========

__launch_bounds__(256)
__global__ void k_agg1(const float* __restrict__ h1s, const float* __restrict__ dinv,
                       const int* __restrict__ rp, const int* __restrict__ csr_src,
                       float* __restrict__ agg1, int n) {
  int gid = blockIdx.x * 256 + threadIdx.x;
  int v = gid >> 6, f = gid & 63;
  if (v >= n) return;
  int beg = rp[v], end = rp[v + 1];
  float a0 = h1s[(size_t)v * 64 + f];  // self term
  float a1 = 0.f, a2 = 0.f, a3 = 0.f, a4 = 0.f, a5 = 0.f, a6 = 0.f, a7 = 0.f;
  for (int j = beg; j < end; j += 8) {
    int s0 = csr_src[j];
    int s1 = csr_src[j + 1];
    int s2 = csr_src[j + 2];
    int s3 = csr_src[j + 3];
    int s4 = csr_src[j + 4];
    int s5 = csr_src[j + 5];
    int s6 = csr_src[j + 6];
    int s7 = csr_src[j + 7];
    s1 = (j + 1 < end) ? s1 : n;
    s2 = (j + 2 < end) ? s2 : n;
    s3 = (j + 3 < end) ? s3 : n;
    s4 = (j + 4 < end) ? s4 : n;
    s5 = (j + 5 < end) ? s5 : n;
    s6 = (j + 6 < end) ? s6 : n;
    s7 = (j + 7 < end) ? s7 : n;
    a0 += h1s[(size_t)s0 * 64 + f];
    a1 += h1s[(size_t)s1 * 64 + f];
    a2 += h1s[(size_t)s2 * 64 + f];
    a3 += h1s[(size_t)s3 * 64 + f];
    a4 += h1s[(size_t)s4 * 64 + f];
    a5 += h1s[(size_t)s5 * 64 + f];
    a6 += h1s[(size_t)s6 * 64 + f];
    a7 += h1s[(size_t)s7 * 64 + f];
  }
  float acc = ((a0 + a1) + (a2 + a3)) + ((a4 + a5) + (a6 + a7));
  agg1[(size_t)v * 64 + f] = dinv[v] * acc;
}

// ======================= GEMM2: h2s = dinv[r] * (relu(agg1 + b1) @ W2^T) ==========
// 256 rows/block, K=64 in 2 chunks of 32; bias+relu fused into LDS staging.
// Thread t: 4 rows (rg=t>>2, 0..63), 8 cols (cg=t&3).

__launch_bounds__(256)
__global__ void k_gemm2(const float* __restrict__ agg1, const float* __restrict__ b1,
                        const float* __restrict__ W2, const float* __restrict__ dinv,
                        float* __restrict__ h2s, int n) {
  __shared__ float4 sW4[32 * 16];   // 8 KB
  __shared__ float4 sX4[256 * 8];   // 32 KB
  int t = threadIdx.x;
  const float4* W24 = (const float4*)W2;
  const float4* a4 = (const float4*)agg1;
  const float4* b14 = (const float4*)b1;
#pragma unroll
  for (int p = 0; p < 2; ++p) {
    int q = t + 256 * p;
    int c = q >> 4, m = q & 15;
    sW4[c * 16 + (m ^ ((c >> 3) & 7))] = W24[c * 16 + m];
  }
  int cg = t & 3;        // cols cg*8 .. cg*8+7
  int rg = t >> 2;       // rows rg*4 .. rg*4+3 (0..63)
  int rbase = blockIdx.x * 256;
  int r0 = rbase + rg * 4;
  float acc[4][8] = {{0.f}};
  for (int ci = 0; ci < 2; ++ci) {
    __syncthreads();
#pragma unroll
    for (int p = 0; p < 8; ++p) {
      int q = t + 256 * p;
      int r = q >> 3, s = q & 7;
      int gr = rbase + r;
      float4 v = make_float4(0.f, 0.f, 0.f, 0.f);
      if (gr < n) {
        float4 a = a4[(size_t)gr * 16 + ci * 8 + s];
        float4 b = b14[ci * 8 + s];
        v = make_float4(fmaxf(a.x + b.x, 0.f), fmaxf(a.y + b.y, 0.f),
                        fmaxf(a.z + b.z, 0.f), fmaxf(a.w + b.w, 0.f));
      }
      sX4[r * 8 + (s ^ ((r >> 2) & 7))] = v;
    }
    __syncthreads();
#pragma unroll
    for (int k4 = 0; k4 < 8; ++k4) {
      int kf4 = ci * 8 + k4;
      float4 xv[4], wv[8];
#pragma unroll
      for (int i = 0; i < 4; ++i)
        xv[i] = sX4[(rg * 4 + i) * 8 + (k4 ^ (rg & 7))];
#pragma unroll
      for (int j = 0; j < 8; ++j)
        wv[j] = sW4[(cg * 8 + j) * 16 + (kf4 ^ cg)];
#pragma unroll
      for (int i = 0; i < 4; ++i)
#pragma unroll
        for (int j = 0; j < 8; ++j) {
          acc[i][j] = fmaf(xv[i].x, wv[j].x, acc[i][j]);
          acc[i][j] = fmaf(xv[i].y, wv[j].y, acc[i][j]);
          acc[i][j] = fmaf(xv[i].z, wv[j].z, acc[i][j]);
          acc[i][j] = fmaf(xv[i].w, wv[j].w, acc[i][j]);
        }
    }
  }
  float4* h2s4 = (float4*)h2s;
#pragma unroll
  for (int i = 0; i < 4; ++i) {
    int gr = r0 + i;
    if (gr < n) {
      float dv = dinv[gr];
      float4 o0 = make_float4(acc[i][0] * dv, acc[i][1] * dv, acc[i][2] * dv,
                              acc[i][3] * dv);
      float4 o1 = make_float4(acc[i][4] * dv, acc[i][5] * dv, acc[i][6] * dv,
                              acc[i][7] * dv);
      h2s4[(size_t)gr * 8 + cg * 2] = o0;
      h2s4[(size_t)gr * 8 + cg * 2 + 1] = o1;
    }
  }
}

// ======================= agg2: gather, 32 feats (half-wave per node), unroll 8 =====

__launch_bounds__(256)
__global__ void k_agg2(const float* __restrict__ h2s, const float* __restrict__ dinv,
                       const int* __restrict__ rp, const int* __restrict__ csr_src,
                       const float* __restrict__ b2, float* __restrict__ out, int n) {
  int gid = blockIdx.x * 256 + threadIdx.x;
  int v = gid >> 5, f = gid & 31;
  if (v >= n) return;
  int beg = rp[v], end = rp[v + 1];
  float a0 = h2s[(size_t)v * 32 + f];  // self term
  float a1 = 0.f, a2 = 0.f, a3 = 0.f, a4 = 0.f, a5 = 0.f, a6 = 0.f, a7 = 0.f;
  for (int j = beg; j < end; j += 8) {
    int s0 = csr_src[j];
    int s1 = csr_src[j + 1];
    int s2 = csr_src[j + 2];
    int s3 = csr_src[j + 3];
    int s4 = csr_src[j + 4];
    int s5 = csr_src[j + 5];
    int s6 = csr_src[j + 6];
    int s7 = csr_src[j + 7];
    s1 = (j + 1 < end) ? s1 : n;
    s2 = (j + 2 < end) ? s2 : n;
    s3 = (j + 3 < end) ? s3 : n;
    s4 = (j + 4 < end) ? s4 : n;
    s5 = (j + 5 < end) ? s5 : n;
    s6 = (j + 6 < end) ? s6 : n;
    s7 = (j + 7 < end) ? s7 : n;
    a0 += h2s[(size_t)s0 * 32 + f];
    a1 += h2s[(size_t)s1 * 32 + f];
    a2 += h2s[(size_t)s2 * 32 + f];
    a3 += h2s[(size_t)s3 * 32 + f];
    a4 += h2s[(size_t)s4 * 32 + f];
    a5 += h2s[(size_t)s5 * 32 + f];
    a6 += h2s[(size_t)s6 * 32 + f];
    a7 += h2s[(size_t)s7 * 32 + f];
  }
  float acc = ((a0 + a1) + (a2 + a3)) + ((a4 + a5) + (a6 + a7));
  out[(size_t)v * 32 + f] = fmaf(dinv[v], acc, b2[f]);
}

// ======================= launcher =======================

extern "C" void kernel_launch(void* const* d_in, const int* in_sizes, int n_in,
                              void* d_out, int out_size, void* d_ws, size_t ws_size,
                              hipStream_t stream) {
  const float* x = (const float*)d_in[0];
  const int* ei = (const int*)d_in[1];
  const float* W1 = (const float*)d_in[2];
  const float* b1 = (const float*)d_in[3];
  const float* W2 = (const float*)d_in[4];
  const float* b2 = (const float*)d_in[5];
  float* out = (float*)d_out;

  const int n = in_sizes[0] / 128;  // 100000
  const int e = in_sizes[1] / 2;    // 1600000
  const int* src = ei;
  const int* dst = ei + e;

  const int NB = (n + 127) >> 7;          // coarse buckets (782)
  const int m = NB * G1;                  // count-matrix size
  const int chunk = (e + G1 - 1) / G1;    // edges per partition block
  const int NC = (m + 1 + 1023) / 1024;   // scan chunks

  char* base = (char*)d_ws;
  size_t off = 0;
  auto alloc = [&](size_t bytes) {
    char* p = base + off;
    off = (off + bytes + 255) & ~(size_t)255;
    return p;
  };
  int* C = (int*)alloc((size_t)m * 4);
  int* Cs = (int*)alloc((size_t)(m + 1) * 4);
  int* bsum = (int*)alloc(1024 * 4);
  int* bpack = (int*)alloc((size_t)e * 4);
  int* rp = (int*)alloc((size_t)(n + 1) * 4);
  int* csr_src = (int*)alloc((size_t)(e + 8) * 4);  // +8 pad for unrolled reads
  float* dinv = (float*)alloc((size_t)n * 4);
  float* h1s = (float*)alloc((size_t)(n + 1) * 64 * 4);  // +1 zero row
  float* agg1 = (float*)alloc((size_t)n * 64 * 4);
  float* h2s = (float*)alloc((size_t)(n + 1) * 32 * 4);  // +1 zero row

  // CSR build (no global atomics)
  k_zrow<<<1, 128, 0, stream>>>(h1s, h2s, n);
  k_pcount<<<G1, 256, 0, stream>>>(dst, C, e, NB, chunk);
  k_scan_chunk<<<NC, 256, 0, stream>>>(C, Cs, bsum, m);
  k_scan_bsum<<<1, 256, 0, stream>>>(bsum, NC);
  k_add<<<(m + 255) / 256, 256, 0, stream>>>(Cs, bsum, m);
  k_partition<<<G1, 256, 0, stream>>>(src, dst, Cs, bpack, e, NB, chunk);
  k_bucket_csr<<<NB, 256, 0, stream>>>(bpack, Cs, rp, dinv, csr_src, n, e, NB);

  // layer 1
  k_gemm1<<<(n + 127) / 128, 256, 0, stream>>>(x, W1, dinv, h1s, n);
  {
    long long total = (long long)n * 64;
    k_agg1<<<(int)((total + 255) / 256), 256, 0, stream>>>(h1s, dinv, rp, csr_src,
                                                           agg1, n);
  }

  // layer 2
  k_gemm2<<<(n + 255) / 256, 256, 0, stream>>>(agg1, b1, W2, dinv, h2s, n);
  {
    long long total = (long long)n * 32;
    k_agg2<<<(int)((total + 255) / 256), 256, 0, stream>>>(h2s, dinv, rp, csr_src, b2,
                                                           out, n);
  }
}

// Round 6
// 252.088 us; speedup vs baseline: 3.2053x; 1.2150x over previous
//
#include <hip/hip_runtime.h>

#define THREADS 256
#define G1 256          // partition blocks
#define MAXNB 4096      // max coarse buckets (n <= 512k)

// bf16 helpers (self-contained, RNE)
static __device__ __forceinline__ unsigned short f2bf(float f) {
  unsigned u = __float_as_uint(f);
  unsigned r = (u + 0x7fff + ((u >> 16) & 1)) >> 16;
  return (unsigned short)r;
}
static __device__ __forceinline__ float bflo(unsigned w) {
  return __uint_as_float(w << 16);
}
static __device__ __forceinline__ float bfhi(unsigned w) {
  return __uint_as_float(w & 0xffff0000u);
}

// ======================= scan machinery (generic, chunk=1024) =======================

__global__ void k_scan_chunk(const int* __restrict__ cnt, int* __restrict__ rp,
                             int* __restrict__ bsum, int m) {
  __shared__ int s[256];
  int b = blockIdx.x, t = threadIdx.x;
  int base = b * 1024 + t * 4;
  int v[4];
  int sum = 0;
#pragma unroll
  for (int k = 0; k < 4; ++k) {
    int i = base + k;
    v[k] = (i < m) ? cnt[i] : 0;
    sum += v[k];
  }
  s[t] = sum;
  __syncthreads();
  int mine = sum;
  for (int off = 1; off < 256; off <<= 1) {
    int y = (t >= off) ? s[t - off] : 0;
    __syncthreads();
    s[t] += y;
    __syncthreads();
  }
  int run = s[t] - mine;
  if (t == 255) bsum[b] = s[255];
#pragma unroll
  for (int k = 0; k < 4; ++k) {
    int i = base + k;
    if (i <= m) rp[i] = run;
    run += v[k];
  }
}

__global__ void k_scan_bsum(int* __restrict__ bsum, int nb) {
  __shared__ int s[256];
  int t = threadIdx.x;
  int v = (t < nb) ? bsum[t] : 0;
  s[t] = v;
  __syncthreads();
  for (int off = 1; off < 256; off <<= 1) {
    int y = (t >= off) ? s[t - off] : 0;
    __syncthreads();
    s[t] += y;
    __syncthreads();
  }
  if (t < nb) bsum[t] = s[t] - v;
}

__global__ void k_add(int* __restrict__ a, const int* __restrict__ bsum, int m) {
  int i = blockIdx.x * blockDim.x + threadIdx.x;
  if (i < m) a[i] += bsum[i >> 10];
}

// ======================= misc init =======================

// zero row n of h1b (64 bf16 = 16 uints) and h2b (32 bf16 = 8 uints)
__global__ void k_zrow(unsigned* __restrict__ h1b, unsigned* __restrict__ h2b, int n) {
  int t = threadIdx.x;
  if (t < 16) h1b[(size_t)n * 32 + t] = 0u;
  else if (t < 24) h2b[(size_t)n * 16 + (t - 16)] = 0u;
}

// ======================= CSR build: two-phase partition, LDS atomics only ===========

__launch_bounds__(256)
__global__ void k_pcount(const int* __restrict__ dst, int* __restrict__ C, int e,
                         int NB, int chunk) {
  __shared__ int h[MAXNB];
  int blk = blockIdx.x, t = threadIdx.x;
  for (int i = t; i < NB; i += 256) h[i] = 0;
  __syncthreads();
  int beg = blk * chunk;
  int stop = min(e, beg + chunk);
  for (int j = beg + t; j < stop; j += 256) atomicAdd(&h[dst[j] >> 7], 1);
  __syncthreads();
  for (int i = t; i < NB; i += 256) C[i * G1 + blk] = h[i];
}

__launch_bounds__(256)
__global__ void k_partition(const int* __restrict__ src, const int* __restrict__ dst,
                            const int* __restrict__ Cs, int* __restrict__ bpack, int e,
                            int NB, int chunk) {
  __shared__ int cur[MAXNB];
  int blk = blockIdx.x, t = threadIdx.x;
  for (int i = t; i < NB; i += 256) cur[i] = Cs[i * G1 + blk];
  __syncthreads();
  int beg = blk * chunk;
  int stop = min(e, beg + chunk);
  for (int j = beg + t; j < stop; j += 256) {
    int d = dst[j];
    int b = d >> 7;
    int pos = atomicAdd(&cur[b], 1);
    bpack[pos] = (src[j] << 7) | (d & 127);
  }
}

__launch_bounds__(256)
__global__ void k_bucket_csr(const int* __restrict__ bpack, const int* __restrict__ Cs,
                             int* __restrict__ rp, float* __restrict__ dinv,
                             int* __restrict__ csr_src, int n, int e, int NB) {
  __shared__ int cl[128];
  __shared__ int cur[128];
  int blk = blockIdx.x, t = threadIdx.x;
  int base = Cs[blk * G1];
  int end = (blk == NB - 1) ? e : Cs[(blk + 1) * G1];
  if (t < 128) cl[t] = 0;
  __syncthreads();
  for (int j = base + t; j < end; j += 256) atomicAdd(&cl[bpack[j] & 127], 1);
  __syncthreads();
  int own = (t < 128) ? cl[t] : 0;
  for (int off = 1; off < 128; off <<= 1) {
    int y = (t >= off && t < 128) ? cl[t - off] : 0;
    __syncthreads();
    if (t < 128) cl[t] += y;
    __syncthreads();
  }
  if (t < 128) {
    int excl = cl[t] - own;
    int v = (blk << 7) + t;
    if (v < n) {
      rp[v] = base + excl;
      dinv[v] = rsqrtf((float)own + 1.0f);
    }
    cur[t] = base + excl;
  }
  __syncthreads();
  for (int j = base + t; j < end; j += 256) {
    int p = bpack[j];
    int pos = atomicAdd(&cur[p & 127], 1);
    csr_src[pos] = p >> 7;
  }
  if (blk == 0 && t == 0) rp[n] = e;
}

// ======================= GEMM1: h1b[n][64](bf16) = dinv[r] * (x @ W1^T) ==========

__launch_bounds__(256)
__global__ void k_gemm1(const float* __restrict__ x, const float* __restrict__ W1,
                        const float* __restrict__ dinv, unsigned short* __restrict__ h1b,
                        int n) {
  __shared__ float4 sW4[64 * 32];   // 32 KB, full K
  __shared__ float4 sX4[128 * 8];   // 16 KB, K-chunk of 32
  int t = threadIdx.x;
  const float4* W14 = (const float4*)W1;
  const float4* x4 = (const float4*)x;
#pragma unroll
  for (int p = 0; p < 8; ++p) {
    int q = t + 256 * p;
    int c = q >> 5, m = q & 31;
    sW4[c * 32 + (m ^ ((c >> 3) & 7))] = W14[c * 32 + m];
  }
  int cg = t & 7;        // cols cg*8 .. cg*8+7
  int rg = t >> 3;       // rows rg*4 .. rg*4+3 (0..31)
  int rbase = blockIdx.x * 128;
  int r0 = rbase + rg * 4;
  float acc[4][8] = {{0.f}};
  for (int ci = 0; ci < 4; ++ci) {
    __syncthreads();
#pragma unroll
    for (int p = 0; p < 4; ++p) {
      int q = t + 256 * p;
      int r = q >> 3, s = q & 7;
      int gr = rbase + r;
      float4 v = (gr < n) ? x4[(size_t)gr * 32 + ci * 8 + s]
                          : make_float4(0.f, 0.f, 0.f, 0.f);
      sX4[r * 8 + (s ^ ((r >> 2) & 7))] = v;
    }
    __syncthreads();
#pragma unroll
    for (int k4 = 0; k4 < 8; ++k4) {
      int kf4 = ci * 8 + k4;
      float4 xv[4], wv[8];
#pragma unroll
      for (int i = 0; i < 4; ++i)
        xv[i] = sX4[(rg * 4 + i) * 8 + (k4 ^ (rg & 7))];
#pragma unroll
      for (int j = 0; j < 8; ++j)
        wv[j] = sW4[(cg * 8 + j) * 32 + (kf4 ^ cg)];
#pragma unroll
      for (int i = 0; i < 4; ++i)
#pragma unroll
        for (int j = 0; j < 8; ++j) {
          acc[i][j] = fmaf(xv[i].x, wv[j].x, acc[i][j]);
          acc[i][j] = fmaf(xv[i].y, wv[j].y, acc[i][j]);
          acc[i][j] = fmaf(xv[i].z, wv[j].z, acc[i][j]);
          acc[i][j] = fmaf(xv[i].w, wv[j].w, acc[i][j]);
        }
    }
  }
  // epilogue: scale by dinv[row], convert to bf16, store 16B per row
#pragma unroll
  for (int i = 0; i < 4; ++i) {
    int gr = r0 + i;
    if (gr < n) {
      float dv = dinv[gr];
      union {
        unsigned short us[8];
        uint4 u4;
      } pk;
#pragma unroll
      for (int j = 0; j < 8; ++j) pk.us[j] = f2bf(acc[i][j] * dv);
      *(uint4*)&h1b[(size_t)gr * 64 + cg * 8] = pk.u4;
    }
  }
}

// ======================= agg1: bf16 gather, 32 lanes/node x 2 feats, unroll 8 ======
// agg1[v][f] = dinv[v] * ( h1b[v][f] + sum_{s in N(v)} h1b[s][f] )   (fp32 out)

__launch_bounds__(256)
__global__ void k_agg1(const unsigned* __restrict__ h1p, const float* __restrict__ dinv,
                       const int* __restrict__ rp, const int* __restrict__ csr_src,
                       float* __restrict__ agg1, int n) {
  int gid = blockIdx.x * 256 + threadIdx.x;
  int v = gid >> 5, f2 = gid & 31;  // uint index within row (2 feats)
  if (v >= n) return;
  int beg = rp[v], end = rp[v + 1];
  unsigned w0 = h1p[(size_t)v * 32 + f2];  // self
  float ax0 = bflo(w0), ay0 = bfhi(w0);
  float ax1 = 0.f, ay1 = 0.f, ax2 = 0.f, ay2 = 0.f, ax3 = 0.f, ay3 = 0.f;
  float ax4 = 0.f, ay4 = 0.f, ax5 = 0.f, ay5 = 0.f, ax6 = 0.f, ay6 = 0.f;
  float ax7 = 0.f, ay7 = 0.f;
  for (int j = beg; j < end; j += 8) {
    int s0 = csr_src[j];
    int s1 = csr_src[j + 1];
    int s2 = csr_src[j + 2];
    int s3 = csr_src[j + 3];
    int s4 = csr_src[j + 4];
    int s5 = csr_src[j + 5];
    int s6 = csr_src[j + 6];
    int s7 = csr_src[j + 7];
    s1 = (j + 1 < end) ? s1 : n;
    s2 = (j + 2 < end) ? s2 : n;
    s3 = (j + 3 < end) ? s3 : n;
    s4 = (j + 4 < end) ? s4 : n;
    s5 = (j + 5 < end) ? s5 : n;
    s6 = (j + 6 < end) ? s6 : n;
    s7 = (j + 7 < end) ? s7 : n;
    unsigned g0 = h1p[(size_t)s0 * 32 + f2];
    unsigned g1 = h1p[(size_t)s1 * 32 + f2];
    unsigned g2 = h1p[(size_t)s2 * 32 + f2];
    unsigned g3 = h1p[(size_t)s3 * 32 + f2];
    unsigned g4 = h1p[(size_t)s4 * 32 + f2];
    unsigned g5 = h1p[(size_t)s5 * 32 + f2];
    unsigned g6 = h1p[(size_t)s6 * 32 + f2];
    unsigned g7 = h1p[(size_t)s7 * 32 + f2];
    ax0 += bflo(g0); ay0 += bfhi(g0);
    ax1 += bflo(g1); ay1 += bfhi(g1);
    ax2 += bflo(g2); ay2 += bfhi(g2);
    ax3 += bflo(g3); ay3 += bfhi(g3);
    ax4 += bflo(g4); ay4 += bfhi(g4);
    ax5 += bflo(g5); ay5 += bfhi(g5);
    ax6 += bflo(g6); ay6 += bfhi(g6);
    ax7 += bflo(g7); ay7 += bfhi(g7);
  }
  float dv = dinv[v];
  float sx = ((ax0 + ax1) + (ax2 + ax3)) + ((ax4 + ax5) + (ax6 + ax7));
  float sy = ((ay0 + ay1) + (ay2 + ay3)) + ((ay4 + ay5) + (ay6 + ay7));
  *(float2*)&agg1[(size_t)v * 64 + f2 * 2] = make_float2(dv * sx, dv * sy);
}

// ======================= GEMM2: h2b(bf16) = dinv[r] * (relu(agg1 + b1) @ W2^T) =====

__launch_bounds__(256)
__global__ void k_gemm2(const float* __restrict__ agg1, const float* __restrict__ b1,
                        const float* __restrict__ W2, const float* __restrict__ dinv,
                        unsigned short* __restrict__ h2b, int n) {
  __shared__ float4 sW4[32 * 16];   // 8 KB
  __shared__ float4 sX4[256 * 8];   // 32 KB
  int t = threadIdx.x;
  const float4* W24 = (const float4*)W2;
  const float4* a4 = (const float4*)agg1;
  const float4* b14 = (const float4*)b1;
#pragma unroll
  for (int p = 0; p < 2; ++p) {
    int q = t + 256 * p;
    int c = q >> 4, m = q & 15;
    sW4[c * 16 + (m ^ ((c >> 3) & 7))] = W24[c * 16 + m];
  }
  int cg = t & 3;        // cols cg*8 .. cg*8+7
  int rg = t >> 2;       // rows rg*4 .. rg*4+3 (0..63)
  int rbase = blockIdx.x * 256;
  int r0 = rbase + rg * 4;
  float acc[4][8] = {{0.f}};
  for (int ci = 0; ci < 2; ++ci) {
    __syncthreads();
#pragma unroll
    for (int p = 0; p < 8; ++p) {
      int q = t + 256 * p;
      int r = q >> 3, s = q & 7;
      int gr = rbase + r;
      float4 v = make_float4(0.f, 0.f, 0.f, 0.f);
      if (gr < n) {
        float4 a = a4[(size_t)gr * 16 + ci * 8 + s];
        float4 b = b14[ci * 8 + s];
        v = make_float4(fmaxf(a.x + b.x, 0.f), fmaxf(a.y + b.y, 0.f),
                        fmaxf(a.z + b.z, 0.f), fmaxf(a.w + b.w, 0.f));
      }
      sX4[r * 8 + (s ^ ((r >> 2) & 7))] = v;
    }
    __syncthreads();
#pragma unroll
    for (int k4 = 0; k4 < 8; ++k4) {
      int kf4 = ci * 8 + k4;
      float4 xv[4], wv[8];
#pragma unroll
      for (int i = 0; i < 4; ++i)
        xv[i] = sX4[(rg * 4 + i) * 8 + (k4 ^ (rg & 7))];
#pragma unroll
      for (int j = 0; j < 8; ++j)
        wv[j] = sW4[(cg * 8 + j) * 16 + (kf4 ^ cg)];
#pragma unroll
      for (int i = 0; i < 4; ++i)
#pragma unroll
        for (int j = 0; j < 8; ++j) {
          acc[i][j] = fmaf(xv[i].x, wv[j].x, acc[i][j]);
          acc[i][j] = fmaf(xv[i].y, wv[j].y, acc[i][j]);
          acc[i][j] = fmaf(xv[i].z, wv[j].z, acc[i][j]);
          acc[i][j] = fmaf(xv[i].w, wv[j].w, acc[i][j]);
        }
    }
  }
#pragma unroll
  for (int i = 0; i < 4; ++i) {
    int gr = r0 + i;
    if (gr < n) {
      float dv = dinv[gr];
      union {
        unsigned short us[8];
        uint4 u4;
      } pk;
#pragma unroll
      for (int j = 0; j < 8; ++j) pk.us[j] = f2bf(acc[i][j] * dv);
      *(uint4*)&h2b[(size_t)gr * 32 + cg * 8] = pk.u4;
    }
  }
}

// ======================= agg2: bf16 gather, 16 lanes/node x 2 feats, unroll 8 ======
// out[v][f] = b2[f] + dinv[v] * ( h2b[v][f] + sum h2b[s][f] )   (fp32 out)

__launch_bounds__(256)
__global__ void k_agg2(const unsigned* __restrict__ h2p, const float* __restrict__ dinv,
                       const int* __restrict__ rp, const int* __restrict__ csr_src,
                       const float* __restrict__ b2, float* __restrict__ out, int n) {
  int gid = blockIdx.x * 256 + threadIdx.x;
  int v = gid >> 4, f2 = gid & 15;  // uint index within row (2 feats)
  if (v >= n) return;
  int beg = rp[v], end = rp[v + 1];
  unsigned w0 = h2p[(size_t)v * 16 + f2];  // self
  float ax0 = bflo(w0), ay0 = bfhi(w0);
  float ax1 = 0.f, ay1 = 0.f, ax2 = 0.f, ay2 = 0.f, ax3 = 0.f, ay3 = 0.f;
  float ax4 = 0.f, ay4 = 0.f, ax5 = 0.f, ay5 = 0.f, ax6 = 0.f, ay6 = 0.f;
  float ax7 = 0.f, ay7 = 0.f;
  for (int j = beg; j < end; j += 8) {
    int s0 = csr_src[j];
    int s1 = csr_src[j + 1];
    int s2 = csr_src[j + 2];
    int s3 = csr_src[j + 3];
    int s4 = csr_src[j + 4];
    int s5 = csr_src[j + 5];
    int s6 = csr_src[j + 6];
    int s7 = csr_src[j + 7];
    s1 = (j + 1 < end) ? s1 : n;
    s2 = (j + 2 < end) ? s2 : n;
    s3 = (j + 3 < end) ? s3 : n;
    s4 = (j + 4 < end) ? s4 : n;
    s5 = (j + 5 < end) ? s5 : n;
    s6 = (j + 6 < end) ? s6 : n;
    s7 = (j + 7 < end) ? s7 : n;
    unsigned g0 = h2p[(size_t)s0 * 16 + f2];
    unsigned g1 = h2p[(size_t)s1 * 16 + f2];
    unsigned g2 = h2p[(size_t)s2 * 16 + f2];
    unsigned g3 = h2p[(size_t)s3 * 16 + f2];
    unsigned g4 = h2p[(size_t)s4 * 16 + f2];
    unsigned g5 = h2p[(size_t)s5 * 16 + f2];
    unsigned g6 = h2p[(size_t)s6 * 16 + f2];
    unsigned g7 = h2p[(size_t)s7 * 16 + f2];
    ax0 += bflo(g0); ay0 += bfhi(g0);
    ax1 += bflo(g1); ay1 += bfhi(g1);
    ax2 += bflo(g2); ay2 += bfhi(g2);
    ax3 += bflo(g3); ay3 += bfhi(g3);
    ax4 += bflo(g4); ay4 += bfhi(g4);
    ax5 += bflo(g5); ay5 += bfhi(g5);
    ax6 += bflo(g6); ay6 += bfhi(g6);
    ax7 += bflo(g7); ay7 += bfhi(g7);
  }
  float dv = dinv[v];
  float sx = ((ax0 + ax1) + (ax2 + ax3)) + ((ax4 + ax5) + (ax6 + ax7));
  float sy = ((ay0 + ay1) + (ay2 + ay3)) + ((ay4 + ay5) + (ay6 + ay7));
  float2 bv = *(const float2*)&b2[f2 * 2];
  *(float2*)&out[(size_t)v * 32 + f2 * 2] =
      make_float2(fmaf(dv, sx, bv.x), fmaf(dv, sy, bv.y));
}

// ======================= launcher =======================

extern "C" void kernel_launch(void* const* d_in, const int* in_sizes, int n_in,
                              void* d_out, int out_size, void* d_ws, size_t ws_size,
                              hipStream_t stream) {
  const float* x = (const float*)d_in[0];
  const int* ei = (const int*)d_in[1];
  const float* W1 = (const float*)d_in[2];
  const float* b1 = (const float*)d_in[3];
  const float* W2 = (const float*)d_in[4];
  const float* b2 = (const float*)d_in[5];
  float* out = (float*)d_out;

  const int n = in_sizes[0] / 128;  // 100000
  const int e = in_sizes[1] / 2;    // 1600000
  const int* src = ei;
  const int* dst = ei + e;

  const int NB = (n + 127) >> 7;          // coarse buckets (782)
  const int m = NB * G1;                  // count-matrix size
  const int chunk = (e + G1 - 1) / G1;    // edges per partition block
  const int NC = (m + 1 + 1023) / 1024;   // scan chunks

  char* base = (char*)d_ws;
  size_t off = 0;
  auto alloc = [&](size_t bytes) {
    char* p = base + off;
    off = (off + bytes + 255) & ~(size_t)255;
    return p;
  };
  int* C = (int*)alloc((size_t)m * 4);
  int* Cs = (int*)alloc((size_t)(m + 1) * 4);
  int* bsum = (int*)alloc(1024 * 4);
  int* bpack = (int*)alloc((size_t)e * 4);
  int* rp = (int*)alloc((size_t)(n + 1) * 4);
  int* csr_src = (int*)alloc((size_t)(e + 8) * 4);  // +8 pad for unrolled reads
  float* dinv = (float*)alloc((size_t)n * 4);
  unsigned short* h1b = (unsigned short*)alloc((size_t)(n + 1) * 64 * 2);  // bf16
  float* agg1 = (float*)alloc((size_t)n * 64 * 4);
  unsigned short* h2b = (unsigned short*)alloc((size_t)(n + 1) * 32 * 2);  // bf16

  // CSR build (no global atomics)
  k_zrow<<<1, 64, 0, stream>>>((unsigned*)h1b, (unsigned*)h2b, n);
  k_pcount<<<G1, 256, 0, stream>>>(dst, C, e, NB, chunk);
  k_scan_chunk<<<NC, 256, 0, stream>>>(C, Cs, bsum, m);
  k_scan_bsum<<<1, 256, 0, stream>>>(bsum, NC);
  k_add<<<(m + 255) / 256, 256, 0, stream>>>(Cs, bsum, m);
  k_partition<<<G1, 256, 0, stream>>>(src, dst, Cs, bpack, e, NB, chunk);
  k_bucket_csr<<<NB, 256, 0, stream>>>(bpack, Cs, rp, dinv, csr_src, n, e, NB);

  // layer 1
  k_gemm1<<<(n + 127) / 128, 256, 0, stream>>>(x, W1, dinv, h1b, n);
  {
    long long total = (long long)n * 32;
    k_agg1<<<(int)((total + 255) / 256), 256, 0, stream>>>((const unsigned*)h1b, dinv,
                                                           rp, csr_src, agg1, n);
  }

  // layer 2
  k_gemm2<<<(n + 255) / 256, 256, 0, stream>>>(agg1, b1, W2, dinv, h2b, n);
  {
    long long total = (long long)n * 16;
    k_agg2<<<(int)((total + 255) / 256), 256, 0, stream>>>((const unsigned*)h2b, dinv,
                                                           rp, csr_src, b2, out, n);
  }
}